// Round 1
// baseline (1305.855 us; speedup 1.0000x reference)
//
#include <hip/hip_runtime.h>
#include <math.h>

constexpr int NB = 4;      // batch
constexpr int ND = 64;     // feature dim
constexpr int NNN = 4096;  // points
constexpr int NO = 128;    // out channels
constexpr int NK = 16;     // k-nn
constexpr float NEG = 0.01f;
constexpr float BN_EPS = 1e-5f;

// workspace offsets (in floats)
constexpr int OFF_XX    = 0;            // 16384
constexpr int OFF_IDX   = 16384;        // 262144 (ints)
constexpr int OFF_D2    = 278528;       // 262144
constexpr int OFF_Q     = 540672;       // 1048576
constexpr int OFF_K     = 1589248;      // 1048576
constexpr int OFF_V     = 2637824;      // 1048576
constexpr int OFF_FGT   = 3686400;      // 1048576
constexpr int OFF_APRE  = 4734976;      // 2097152  [b][n][o]
constexpr int OFF_BPRE  = 6832128;      // 2097152  [b][n][o]
constexpr int OFF_IMAX  = 8929280;      // 2097152  [b][o][n]
constexpr int OFF_IMIN  = 11026432;     // 2097152  [b][o][n]
constexpr int OFF_ZSEM  = OFF_Q;        // reuse q+k (dead after attn)
constexpr int OFF_ZFULL = OFF_V;        // reuse v+fgt (dead after sem)
constexpr int OFF_STATS = 13123584;     // 6*128: [sum_i,ssq_i, sum_s,ssq_s, sum_f,ssq_f]
constexpr int OFF_COEF  = 13124352;     // 6*128: [a_i,b_i, a_s,b_s, a_f,b_f]
constexpr int OFF_LINV  = 13125120;     // 16384: 1/softmax-rowsum

// ---------------- xx[b][n] = sum_d f^2 ----------------
__global__ void k_xx(const float* __restrict__ f, float* __restrict__ xx) {
  int gid = blockIdx.x * 256 + threadIdx.x;
  int b = gid >> 12, n = gid & 4095;
  const float* fb = f + b * ND * NNN + n;
  float s = 0.f;
#pragma unroll
  for (int d = 0; d < ND; ++d) { float v = fb[d * NNN]; s += v * v; }
  xx[gid] = s;
}

// ---------------- q/k/v = W f + bias  (grid.y selects) ----------------
__global__ __launch_bounds__(256) void k_qkv(const float* __restrict__ f,
    const float* __restrict__ wq, const float* __restrict__ bq,
    const float* __restrict__ wk, const float* __restrict__ bk,
    const float* __restrict__ wv, const float* __restrict__ bv,
    float* __restrict__ outbase) {
  int sel = blockIdx.y;
  const float* W    = (sel == 0) ? wq : (sel == 1) ? wk : wv;
  const float* bias = (sel == 0) ? bq : (sel == 1) ? bk : bv;
  float* out = outbase + sel * (NB * ND * NNN);
  int t = threadIdx.x;
  int c = t & 63;
  int og = __builtin_amdgcn_readfirstlane(t >> 6);  // wave-uniform
  int gcol = blockIdx.x * 64 + c;
  int b = gcol >> 12, n = gcol & 4095;
  const float* fb = f + b * ND * NNN + n;
  float cv[64];
#pragma unroll
  for (int d = 0; d < ND; ++d) cv[d] = fb[d * NNN];
  for (int oi = 0; oi < 16; ++oi) {
    int o = og * 16 + oi;
    const float* wr = W + o * ND;   // wave-uniform -> scalar loads
    float a = bias[o];
#pragma unroll
    for (int d = 0; d < ND; ++d) a += wr[d] * cv[d];
    out[(b * ND + o) * NNN + n] = a;
  }
}

// ---------------- kNN: 4 rows/block, key = 2*inner - xx[n], top-16 ----------------
__global__ __launch_bounds__(256) void k_knn(const float* __restrict__ f, const float* __restrict__ xx,
                                             int* __restrict__ tidx, float* __restrict__ td2) {
  __shared__ float fm[ND * 4];
  __shared__ float redv[4];
  __shared__ int redi[4];
  __shared__ int bcI;
  int t = threadIdx.x;
  int b = blockIdx.x >> 10;
  int m0 = (blockIdx.x & 1023) << 2;
  const float* fb = f + b * ND * NNN;
  { int d = t >> 2, r = t & 3; fm[t] = fb[d * NNN + m0 + r]; }
  __syncthreads();
  float acc[64];
#pragma unroll
  for (int i = 0; i < 64; ++i) acc[i] = 0.f;
  for (int d = 0; d < ND; ++d) {
    float4 fv = *(const float4*)&fm[d * 4];
    const float* frow = fb + d * NNN + t;
#pragma unroll
    for (int j = 0; j < 16; ++j) {
      float cv = frow[j * 256];
      acc[j * 4 + 0] += fv.x * cv;
      acc[j * 4 + 1] += fv.y * cv;
      acc[j * 4 + 2] += fv.z * cv;
      acc[j * 4 + 3] += fv.w * cv;
    }
  }
#pragma unroll
  for (int j = 0; j < 16; ++j) {
    float xv = xx[b * NNN + j * 256 + t];
    acc[j * 4 + 0] = 2.f * acc[j * 4 + 0] - xv;
    acc[j * 4 + 1] = 2.f * acc[j * 4 + 1] - xv;
    acc[j * 4 + 2] = 2.f * acc[j * 4 + 2] - xv;
    acc[j * 4 + 3] = 2.f * acc[j * 4 + 3] - xv;
  }
  int lane = t & 63, w = t >> 6;
#pragma unroll
  for (int r = 0; r < 4; ++r) {
    float mxx = xx[b * NNN + m0 + r];
    for (int kx = 0; kx < NK; ++kx) {
      float bv = -3.4e38f; int bi = 0x7fffffff;
#pragma unroll
      for (int j = 0; j < 16; ++j) {        // ascending col -> ties keep smaller index
        float vj = acc[j * 4 + r];
        if (vj > bv) { bv = vj; bi = j * 256 + t; }
      }
#pragma unroll
      for (int off = 32; off; off >>= 1) {
        float ov = __shfl_down(bv, off);
        int oi = __shfl_down(bi, off);
        if (ov > bv || (ov == bv && oi < bi)) { bv = ov; bi = oi; }
      }
      if (lane == 0) { redv[w] = bv; redi[w] = bi; }
      __syncthreads();
      if (t == 0) {
        float V = redv[0]; int I = redi[0];
#pragma unroll
        for (int u = 1; u < 4; ++u)
          if (redv[u] > V || (redv[u] == V && redi[u] < I)) { V = redv[u]; I = redi[u]; }
        int base = (b * NNN + m0 + r) * NK + kx;
        tidx[base] = I;
        float dd = mxx - V;                 // d^2 = xx[m] - (2 inner - xx[n])
        td2[base] = dd > 0.f ? dd : 0.f;
        bcI = I;
      }
      __syncthreads();
      int I = bcI;
      if ((I & 255) == t) {
        int jwin = I >> 8;
#pragma unroll
        for (int j = 0; j < 16; ++j)
          if (j == jwin) acc[j * 4 + r] = -3.4e38f;
      }
    }
  }
}

// ---------------- attention: 4 rows/block, full-row softmax in LDS ----------------
__global__ __launch_bounds__(256) void k_attn(const float* __restrict__ q,
                                              const float* __restrict__ k,
                                              const float* __restrict__ v,
                                              float* __restrict__ fgt,
                                              float* __restrict__ linv) {
  __shared__ float sl[4 * NNN];           // exactly 64 KB; first 1 KB reused for q-frag
  int t = threadIdx.x;
  int b = blockIdx.x >> 10;
  int m0 = (blockIdx.x & 1023) << 2;
  const float* qb = q + b * ND * NNN;
  const float* kb = k + b * ND * NNN;
  const float* vb = v + b * ND * NNN;
  { int d = t >> 2, r = t & 3; sl[t] = qb[d * NNN + m0 + r]; }
  __syncthreads();
  float acc[64];
#pragma unroll
  for (int i = 0; i < 64; ++i) acc[i] = 0.f;
  for (int d = 0; d < ND; ++d) {
    float4 qv = *(const float4*)&sl[d * 4];
    const float* krow = kb + d * NNN + t;
#pragma unroll
    for (int j = 0; j < 16; ++j) {
      float cv = krow[j * 256];
      acc[j * 4 + 0] += qv.x * cv;
      acc[j * 4 + 1] += qv.y * cv;
      acc[j * 4 + 2] += qv.z * cv;
      acc[j * 4 + 3] += qv.w * cv;
    }
  }
  __syncthreads();                        // done reading q-frag region
#pragma unroll
  for (int j = 0; j < 16; ++j) {
#pragma unroll
    for (int r = 0; r < 4; ++r) sl[r * NNN + j * 256 + t] = acc[j * 4 + r] * 0.125f;
  }
  __syncthreads();
  int lane = t & 63;
  int w = __builtin_amdgcn_readfirstlane(t >> 6);
  float* row = sl + w * NNN;              // wave w owns softmax of row w
  float mx = -3.4e38f;
  for (int j = 0; j < 64; ++j) mx = fmaxf(mx, row[lane + j * 64]);
#pragma unroll
  for (int off = 32; off; off >>= 1) mx = fmaxf(mx, __shfl_down(mx, off));
  mx = __shfl(mx, 0);
  float ls = 0.f;
  for (int j = 0; j < 64; ++j) {
    int c = lane + j * 64;
    float e = __expf(row[c] - mx);
    row[c] = e;
    ls += e;
  }
#pragma unroll
  for (int off = 32; off; off >>= 1) ls += __shfl_down(ls, off);
  if (lane == 0) linv[b * NNN + m0 + w] = 1.f / ls;   // normalization deferred
  __syncthreads();                        // all rows' e visible to all waves
  // PV: wave w handles d in [w*16, w*16+16) for all 4 rows -> v read once/block
  float pacc[64];                         // [dd][r]
#pragma unroll
  for (int i = 0; i < 64; ++i) pacc[i] = 0.f;
  int d0 = w * 16;
  for (int j = 0; j < 64; ++j) {
    int col = lane + j * 64;
    float e0 = sl[0 * NNN + col], e1 = sl[1 * NNN + col];
    float e2 = sl[2 * NNN + col], e3 = sl[3 * NNN + col];
    const float* vp = vb + d0 * NNN + col;
#pragma unroll
    for (int dd = 0; dd < 16; ++dd) {
      float vv = vp[dd * NNN];
      pacc[dd * 4 + 0] += vv * e0;
      pacc[dd * 4 + 1] += vv * e1;
      pacc[dd * 4 + 2] += vv * e2;
      pacc[dd * 4 + 3] += vv * e3;
    }
  }
  float res = 0.f;
#pragma unroll
  for (int i = 0; i < 64; ++i) {
    float x = pacc[i];
#pragma unroll
    for (int m = 1; m < 64; m <<= 1) x += __shfl_xor(x, m);
    if (lane == i) res = x;
  }
  int dd = lane >> 2, r = lane & 3;
  fgt[(b * ND + d0 + dd) * NNN + m0 + r] = res;       // unnormalized
}

// ---------------- A/B2 pre-GEMMs:  out[b][n][o] ----------------
__global__ __launch_bounds__(256) void k_ab(const float* __restrict__ f, const float* __restrict__ wl,
                                            float* __restrict__ Apre, float* __restrict__ Bpre) {
  __shared__ float fl[ND * 64];
  int t = threadIdx.x;
  int b = blockIdx.x >> 6;
  int n0 = (blockIdx.x & 63) << 6;
  for (int e = t; e < ND * 64; e += 256) {
    int d = e >> 6, c = e & 63;
    fl[e] = f[b * ND * NNN + d * NNN + n0 + c];
  }
  __syncthreads();
  int lane = t & 63;
  int w = __builtin_amdgcn_readfirstlane(t >> 6);
#pragma unroll 1
  for (int g = 0; g < 8; ++g) {
    float acc[8] = {0, 0, 0, 0, 0, 0, 0, 0};
    int p0 = w * 64 + g * 8;
    for (int d = 0; d < ND; ++d) {
      float fv = fl[d * 64 + lane];
#pragma unroll
      for (int u = 0; u < 8; ++u) {
        int p = p0 + u;
        int o = p & 127, sel = p >> 7;
        acc[u] += wl[o * 129 + sel * 64 + d] * fv;    // wave-uniform -> scalar loads
      }
    }
#pragma unroll
    for (int u = 0; u < 8; ++u) {
      int p = p0 + u;
      int o = p & 127, sel = p >> 7;
      float* outp = sel ? Bpre : Apre;
      outp[(b * NNN + n0 + lane) * NO + o] = acc[u];
    }
  }
}

// ---------------- intra: y = A + B2[idx] + w128*dist ; max/min over k + stats ----------------
__global__ __launch_bounds__(128) void k_intra(const float* __restrict__ Apre, const float* __restrict__ Bpre,
                                               const int* __restrict__ tidx, const float* __restrict__ td2,
                                               const float* __restrict__ wl, float* __restrict__ imax,
                                               float* __restrict__ imin, float* __restrict__ stats) {
  __shared__ int sidx[32 * NK];
  __shared__ float sdst[32 * NK];
  int t = threadIdx.x;
  int b = blockIdx.x >> 7;
  int n0 = (blockIdx.x & 127) << 5;
  for (int e = t; e < 32 * NK; e += 128) {
    int base = (b * NNN + n0 + (e >> 4)) * NK + (e & 15);
    sidx[e] = tidx[base];
    sdst[e] = sqrtf(td2[base]);
  }
  __syncthreads();
  int o = t;
  float w128 = wl[o * 129 + 128];
  float ssum = 0.f, ssq = 0.f;
  for (int c = 0; c < 32; ++c) {
    float a = Apre[(b * NNN + n0 + c) * NO + o];
    float mx = -3.4e38f, mn = 3.4e38f;
#pragma unroll
    for (int kx = 0; kx < NK; ++kx) {
      int id = sidx[c * NK + kx];
      float y = a + Bpre[(b * NNN + id) * NO + o] + w128 * sdst[c * NK + kx];
      mx = fmaxf(mx, y); mn = fminf(mn, y);
      ssum += y; ssq += y * y;
    }
    imax[(b * NO + o) * NNN + n0 + c] = mx;
    imin[(b * NO + o) * NNN + n0 + c] = mn;
  }
  atomicAdd(&stats[o], ssum);
  atomicAdd(&stats[NO + o], ssq);
}

// ---------------- sem: z = w_sem * (fgt * linv)  -> [b][o][n] ----------------
__global__ __launch_bounds__(256) void k_sem(const float* __restrict__ fgt, const float* __restrict__ linv,
                                             const float* __restrict__ wsem, float* __restrict__ zsem) {
  __shared__ float fl[ND * 64];
  int t = threadIdx.x;
  int b = blockIdx.x >> 6;
  int n0 = (blockIdx.x & 63) << 6;
  for (int e = t; e < ND * 64; e += 256) {
    int d = e >> 6, c = e & 63;
    fl[e] = fgt[b * ND * NNN + d * NNN + n0 + c] * linv[b * NNN + n0 + c];
  }
  __syncthreads();
  int lane = t & 63;
  int ob = __builtin_amdgcn_readfirstlane((t >> 6) * 32);
#pragma unroll 1
  for (int g = 0; g < 4; ++g) {
    float acc[8] = {0, 0, 0, 0, 0, 0, 0, 0};
    for (int d = 0; d < ND; ++d) {
      float fv = fl[d * 64 + lane];
#pragma unroll
      for (int u = 0; u < 8; ++u) acc[u] += wsem[(ob + g * 8 + u) * ND + d] * fv;
    }
#pragma unroll
    for (int u = 0; u < 8; ++u)
      zsem[(b * NO + ob + g * 8 + u) * NNN + n0 + lane] = acc[u];
  }
}

// ---------------- per-channel sum/ssq over [b][o][n] (one block per o) ----------------
__global__ void k_stats(const float* __restrict__ zz, float* __restrict__ sout) {
  int o = blockIdx.x, t = threadIdx.x;
  float s = 0.f, q = 0.f;
  for (int b2 = 0; b2 < NB; ++b2) {
    const float* p = zz + (size_t)(b2 * NO + o) * NNN;
    for (int n = t; n < NNN; n += 256) { float v = p[n]; s += v; q += v * v; }
  }
#pragma unroll
  for (int off = 32; off; off >>= 1) { s += __shfl_down(s, off); q += __shfl_down(q, off); }
  __shared__ float rs[4], rq[4];
  int lane = t & 63, w = t >> 6;
  if (lane == 0) { rs[w] = s; rq[w] = q; }
  __syncthreads();
  if (t == 0) {
    sout[o]      = rs[0] + rs[1] + rs[2] + rs[3];
    sout[NO + o] = rq[0] + rq[1] + rq[2] + rq[3];
  }
}

// ---------------- finalize BN -> per-channel affine (a, b) ----------------
__global__ void k_fin(const float* __restrict__ stats, const float* __restrict__ g,
                      const float* __restrict__ be, float cnt_inv, float* __restrict__ coef) {
  int o = threadIdx.x;
  float mean = stats[o] * cnt_inv;
  float var = stats[NO + o] * cnt_inv - mean * mean;
  var = var > 0.f ? var : 0.f;
  float a = g[o] * rsqrtf(var + BN_EPS);
  coef[o] = a;
  coef[NO + o] = be[o] - mean * a;
}

// ---------------- full: z = w_full * lrelu(BN(cat)) ----------------
__global__ __launch_bounds__(256) void k_full(const float* __restrict__ imax, const float* __restrict__ imin,
                                              const float* __restrict__ zsem, const float* __restrict__ wfull,
                                              const float* __restrict__ coef, float* __restrict__ zfull) {
  __shared__ float fl[2 * NO * 64];       // exactly 64 KB
  int t = threadIdx.x;
  int b = blockIdx.x >> 6;
  int n0 = (blockIdx.x & 63) << 6;
  for (int e = t; e < 2 * NO * 64; e += 256) {
    int c = e >> 6, col = e & 63;
    float aa, bb, x;
    if (c < NO) {
      aa = coef[c]; bb = coef[NO + c];
      const float* src = (aa >= 0.f) ? imax : imin;   // max commutes with monotone affine
      x = src[(b * NO + c) * NNN + n0 + col];
    } else {
      int c2 = c - NO;
      aa = coef[2 * NO + c2]; bb = coef[3 * NO + c2];
      x = zsem[(b * NO + c2) * NNN + n0 + col];
    }
    float y = aa * x + bb;
    fl[e] = (y >= 0.f) ? y : NEG * y;
  }
  __syncthreads();
  int lane = t & 63;
  int ob = __builtin_amdgcn_readfirstlane((t >> 6) * 32);
#pragma unroll 1
  for (int g = 0; g < 4; ++g) {
    float acc[8] = {0, 0, 0, 0, 0, 0, 0, 0};
    for (int c = 0; c < 2 * NO; ++c) {
      float fv = fl[c * 64 + lane];
#pragma unroll
      for (int u = 0; u < 8; ++u) acc[u] += wfull[(ob + g * 8 + u) * (2 * NO) + c] * fv;
    }
#pragma unroll
    for (int u = 0; u < 8; ++u)
      zfull[(b * NO + ob + g * 8 + u) * NNN + n0 + lane] = acc[u];
  }
}

// ---------------- out = lrelu(a*z + b) ----------------
__global__ void k_out(const float* __restrict__ zfull, const float* __restrict__ coef,
                      float* __restrict__ out) {
  int gid = blockIdx.x * 256 + threadIdx.x;
  int o = (gid >> 12) & 127;
  float y = coef[o] * zfull[gid] + coef[NO + o];
  out[gid] = (y >= 0.f) ? y : NEG * y;
}

extern "C" void kernel_launch(void* const* d_in, const int* in_sizes, int n_in,
                              void* d_out, int out_size, void* d_ws, size_t ws_size,
                              hipStream_t stream) {
  (void)in_sizes; (void)n_in; (void)out_size; (void)ws_size;
  const float* f       = (const float*)d_in[0];
  const float* w_local = (const float*)d_in[1];
  const float* g_local = (const float*)d_in[2];
  const float* b_local = (const float*)d_in[3];
  const float* w_sem   = (const float*)d_in[4];
  const float* g_sem   = (const float*)d_in[5];
  const float* b_sem   = (const float*)d_in[6];
  const float* w_full  = (const float*)d_in[7];
  const float* g_full  = (const float*)d_in[8];
  const float* b_full  = (const float*)d_in[9];
  const float* wq = (const float*)d_in[10];
  const float* bq = (const float*)d_in[11];
  const float* wk = (const float*)d_in[12];
  const float* bk = (const float*)d_in[13];
  const float* wv = (const float*)d_in[14];
  const float* bv = (const float*)d_in[15];
  float* Wp = (float*)d_ws;

  hipMemsetAsync(Wp + OFF_STATS, 0, 2 * NO * sizeof(float), stream);  // intra atomic stats
  k_xx  <<<NB * NNN / 256, 256, 0, stream>>>(f, Wp + OFF_XX);
  k_qkv <<<dim3(NB * NNN / 64, 3), 256, 0, stream>>>(f, wq, bq, wk, bk, wv, bv, Wp + OFF_Q);
  k_knn <<<NB * (NNN / 4), 256, 0, stream>>>(f, Wp + OFF_XX, (int*)(Wp + OFF_IDX), Wp + OFF_D2);
  k_attn<<<NB * (NNN / 4), 256, 0, stream>>>(Wp + OFF_Q, Wp + OFF_K, Wp + OFF_V,
                                             Wp + OFF_FGT, Wp + OFF_LINV);
  k_ab  <<<NB * (NNN / 64), 256, 0, stream>>>(f, w_local, Wp + OFF_APRE, Wp + OFF_BPRE);
  k_intra<<<NB * (NNN / 32), 128, 0, stream>>>(Wp + OFF_APRE, Wp + OFF_BPRE,
                                               (const int*)(Wp + OFF_IDX), Wp + OFF_D2,
                                               w_local, Wp + OFF_IMAX, Wp + OFF_IMIN, Wp + OFF_STATS);
  k_sem <<<NB * (NNN / 64), 256, 0, stream>>>(Wp + OFF_FGT, Wp + OFF_LINV, w_sem, Wp + OFF_ZSEM);
  k_stats<<<NO, 256, 0, stream>>>(Wp + OFF_ZSEM, Wp + OFF_STATS + 2 * NO);
  k_fin <<<1, NO, 0, stream>>>(Wp + OFF_STATS,          g_local, b_local,
                               1.f / (float)(NB * NNN * NK), Wp + OFF_COEF);
  k_fin <<<1, NO, 0, stream>>>(Wp + OFF_STATS + 2 * NO, g_sem, b_sem,
                               1.f / (float)(NB * NNN), Wp + OFF_COEF + 2 * NO);
  k_full<<<NB * (NNN / 64), 256, 0, stream>>>(Wp + OFF_IMAX, Wp + OFF_IMIN, Wp + OFF_ZSEM,
                                              w_full, Wp + OFF_COEF, Wp + OFF_ZFULL);
  k_stats<<<NO, 256, 0, stream>>>(Wp + OFF_ZFULL, Wp + OFF_STATS + 4 * NO);
  k_fin <<<1, NO, 0, stream>>>(Wp + OFF_STATS + 4 * NO, g_full, b_full,
                               1.f / (float)(NB * NNN), Wp + OFF_COEF + 4 * NO);
  k_out <<<NB * NO * NNN / 256, 256, 0, stream>>>(Wp + OFF_ZFULL, Wp + OFF_COEF + 4 * NO,
                                                  (float*)d_out);
}

// Round 2
// 967.819 us; speedup vs baseline: 1.3493x; 1.3493x over previous
//
#include <hip/hip_runtime.h>
#include <math.h>

constexpr int NB = 4;      // batch
constexpr int ND = 64;     // feature dim
constexpr int NNN = 4096;  // points
constexpr int NO = 128;    // out channels
constexpr int NK = 16;     // k-nn
constexpr float NEG = 0.01f;
constexpr float BN_EPS = 1e-5f;

typedef unsigned short u16;
typedef unsigned int u32;
typedef __attribute__((ext_vector_type(8))) short short8;
typedef __attribute__((ext_vector_type(4))) float floatx4;

// workspace offsets (in floats) — same map as R1
constexpr int OFF_XX    = 0;
constexpr int OFF_IDX   = 16384;
constexpr int OFF_D2    = 278528;
constexpr int OFF_Q     = 540672;       // qb16 bf16 [b][n][d]
constexpr int OFF_K     = 1589248;      // kb16 bf16 [b][n][d]
constexpr int OFF_V     = 2637824;      // vb16 bf16 [b][d][n]
constexpr int OFF_FGT   = 3686400;      // fgt fp32 [b][n][d] (unnormalized)
constexpr int OFF_APRE  = 4734976;
constexpr int OFF_BPRE  = 6832128;
constexpr int OFF_IMAX  = 8929280;
constexpr int OFF_IMIN  = 11026432;
constexpr int OFF_ZSEM  = OFF_Q;
constexpr int OFF_ZFULL = OFF_V;
constexpr int OFF_STATS = 13123584;
constexpr int OFF_COEF  = 13124352;
constexpr int OFF_LINV  = 13125120;

__device__ __forceinline__ u16 f2b(float x) {       // fp32 -> bf16 RNE
  u32 u = __builtin_bit_cast(u32, x);
  u += 0x7fffu + ((u >> 16) & 1u);
  return (u16)(u >> 16);
}

// ---------------- xx[b][n] = sum_d f^2 ----------------
__global__ void k_xx(const float* __restrict__ f, float* __restrict__ xx) {
  int gid = blockIdx.x * 256 + threadIdx.x;
  int b = gid >> 12, n = gid & 4095;
  const float* fb = f + b * ND * NNN + n;
  float s = 0.f;
#pragma unroll
  for (int d = 0; d < ND; ++d) { float v = fb[d * NNN]; s += v * v; }
  xx[gid] = s;
}

// ---------------- q/k/v = W f + bias -> bf16 (q,k: [b][n][d]; v: [b][d][n]) ----------------
__global__ __launch_bounds__(256) void k_qkv(const float* __restrict__ f,
    const float* __restrict__ wq, const float* __restrict__ bq,
    const float* __restrict__ wk, const float* __restrict__ bk,
    const float* __restrict__ wv, const float* __restrict__ bv,
    u16* __restrict__ qb, u16* __restrict__ kb, u16* __restrict__ vb) {
  int sel = blockIdx.y;
  const float* W    = (sel == 0) ? wq : (sel == 1) ? wk : wv;
  const float* bias = (sel == 0) ? bq : (sel == 1) ? bk : bv;
  int t = threadIdx.x;
  int lane = t & 63;
  int og = __builtin_amdgcn_readfirstlane(t >> 6);
  int gcol = blockIdx.x * 64 + lane;
  int b = gcol >> 12, n = gcol & 4095;
  const float* fb = f + b * ND * NNN + n;
  float cv[64];
#pragma unroll
  for (int d = 0; d < ND; ++d) cv[d] = fb[d * NNN];
  float acc[16];
#pragma unroll 1
  for (int oi = 0; oi < 16; ++oi) {
    int o = og * 16 + oi;
    const float* wr = W + o * ND;
    float a = bias[o];
#pragma unroll
    for (int d = 0; d < ND; ++d) a += wr[d] * cv[d];
    acc[oi] = a;
  }
  if (sel == 2) {
#pragma unroll
    for (int oi = 0; oi < 16; ++oi)
      vb[(size_t)(b * ND + og * 16 + oi) * NNN + n] = f2b(acc[oi]);
  } else {
    short8 p0, p1;
#pragma unroll
    for (int oi = 0; oi < 8; ++oi) { p0[oi] = (short)f2b(acc[oi]); p1[oi] = (short)f2b(acc[8 + oi]); }
    u16* dst = (sel ? kb : qb) + (size_t)(b * NNN + n) * ND + og * 16;
    *(short8*)dst = p0;
    *(short8*)(dst + 8) = p1;
  }
}

// ---------------- kNN (unchanged, fp32) ----------------
__global__ __launch_bounds__(256) void k_knn(const float* __restrict__ f, const float* __restrict__ xx,
                                             int* __restrict__ tidx, float* __restrict__ td2) {
  __shared__ float fm[ND * 4];
  __shared__ float redv[4];
  __shared__ int redi[4];
  __shared__ int bcI;
  int t = threadIdx.x;
  int b = blockIdx.x >> 10;
  int m0 = (blockIdx.x & 1023) << 2;
  const float* fb = f + b * ND * NNN;
  { int d = t >> 2, r = t & 3; fm[t] = fb[d * NNN + m0 + r]; }
  __syncthreads();
  float acc[64];
#pragma unroll
  for (int i = 0; i < 64; ++i) acc[i] = 0.f;
  for (int d = 0; d < ND; ++d) {
    float4 fv = *(const float4*)&fm[d * 4];
    const float* frow = fb + d * NNN + t;
#pragma unroll
    for (int j = 0; j < 16; ++j) {
      float cv = frow[j * 256];
      acc[j * 4 + 0] += fv.x * cv;
      acc[j * 4 + 1] += fv.y * cv;
      acc[j * 4 + 2] += fv.z * cv;
      acc[j * 4 + 3] += fv.w * cv;
    }
  }
#pragma unroll
  for (int j = 0; j < 16; ++j) {
    float xv = xx[b * NNN + j * 256 + t];
    acc[j * 4 + 0] = 2.f * acc[j * 4 + 0] - xv;
    acc[j * 4 + 1] = 2.f * acc[j * 4 + 1] - xv;
    acc[j * 4 + 2] = 2.f * acc[j * 4 + 2] - xv;
    acc[j * 4 + 3] = 2.f * acc[j * 4 + 3] - xv;
  }
  int lane = t & 63, w = t >> 6;
#pragma unroll
  for (int r = 0; r < 4; ++r) {
    float mxx = xx[b * NNN + m0 + r];
    for (int kx = 0; kx < NK; ++kx) {
      float bv = -3.4e38f; int bi = 0x7fffffff;
#pragma unroll
      for (int j = 0; j < 16; ++j) {
        float vj = acc[j * 4 + r];
        if (vj > bv) { bv = vj; bi = j * 256 + t; }
      }
#pragma unroll
      for (int off = 32; off; off >>= 1) {
        float ov = __shfl_down(bv, off);
        int oi = __shfl_down(bi, off);
        if (ov > bv || (ov == bv && oi < bi)) { bv = ov; bi = oi; }
      }
      if (lane == 0) { redv[w] = bv; redi[w] = bi; }
      __syncthreads();
      if (t == 0) {
        float V = redv[0]; int I = redi[0];
#pragma unroll
        for (int u = 1; u < 4; ++u)
          if (redv[u] > V || (redv[u] == V && redi[u] < I)) { V = redv[u]; I = redi[u]; }
        int base = (b * NNN + m0 + r) * NK + kx;
        tidx[base] = I;
        float dd = mxx - V;
        td2[base] = dd > 0.f ? dd : 0.f;
        bcI = I;
      }
      __syncthreads();
      int I = bcI;
      if ((I & 255) == t) {
        int jwin = I >> 8;
#pragma unroll
        for (int j = 0; j < 16; ++j)
          if (j == jwin) acc[j * 4 + r] = -3.4e38f;
      }
    }
  }
}

// ---------------- attention: MFMA bf16, 16 rows/block, P-chunk (16x512) in LDS ----------------
__global__ __launch_bounds__(256) void k_attn(const u16* __restrict__ qb,
                                              const u16* __restrict__ kb,
                                              const u16* __restrict__ vb,
                                              float* __restrict__ fgt,
                                              float* __restrict__ linv) {
  __shared__ __align__(16) u16 P[16 * 520];
  __shared__ float rsum[4][16];
  int t = threadIdx.x;
  int lane = t & 63;
  int w = __builtin_amdgcn_readfirstlane(t >> 6);
  int quad = lane >> 4;
  int l15 = lane & 15;
  int b = blockIdx.x >> 8;
  int m0 = (blockIdx.x & 255) << 4;
  const u16* qrow = qb + (size_t)(b * NNN + m0 + l15) * ND + quad * 8;
  short8 qa0 = *(const short8*)(qrow);
  short8 qa1 = *(const short8*)(qrow + 32);
  const u16* kbase = kb + (size_t)b * NNN * ND;
  const u16* vrow  = vb + (size_t)(b * ND + w * 16 + l15) * NNN;
  floatx4 c2 = {0.f, 0.f, 0.f, 0.f};
  float rs[4] = {0.f, 0.f, 0.f, 0.f};
#pragma unroll 1
  for (int it = 0; it < 8; ++it) {
    int nchunk = it * 512;
#pragma unroll 1
    for (int ct = 0; ct < 8; ++ct) {
      int cc0 = (w * 8 + ct) * 16;
      const u16* krow = kbase + (size_t)(nchunk + cc0 + l15) * ND + quad * 8;
      short8 kf0 = *(const short8*)(krow);
      short8 kf1 = *(const short8*)(krow + 32);
      floatx4 acc = {0.f, 0.f, 0.f, 0.f};
      acc = __builtin_amdgcn_mfma_f32_16x16x32_bf16(qa0, kf0, acc, 0, 0, 0);
      acc = __builtin_amdgcn_mfma_f32_16x16x32_bf16(qa1, kf1, acc, 0, 0, 0);
      int ccol = cc0 + l15;
#pragma unroll
      for (int r = 0; r < 4; ++r) {
        float e = __expf(acc[r] * 0.125f);
        rs[r] += e;
        P[(quad * 4 + r) * 520 + ccol] = f2b(e);
      }
    }
    __syncthreads();
    const u16* vp = vrow + nchunk + quad * 8;
#pragma unroll
    for (int kk = 0; kk < 16; ++kk) {
      short8 a2 = *(const short8*)&P[l15 * 520 + kk * 32 + quad * 8];
      short8 b2 = *(const short8*)(vp + kk * 32);
      c2 = __builtin_amdgcn_mfma_f32_16x16x32_bf16(a2, b2, c2, 0, 0, 0);
    }
    __syncthreads();
  }
#pragma unroll
  for (int r = 0; r < 4; ++r) {
    float v = rs[r];
    v += __shfl_xor(v, 1); v += __shfl_xor(v, 2);
    v += __shfl_xor(v, 4); v += __shfl_xor(v, 8);
    rs[r] = v;
  }
  if (l15 == 0) {
#pragma unroll
    for (int r = 0; r < 4; ++r) rsum[w][quad * 4 + r] = rs[r];
  }
#pragma unroll
  for (int r = 0; r < 4; ++r)
    fgt[(size_t)(b * NNN + m0 + quad * 4 + r) * ND + w * 16 + l15] = c2[r];
  __syncthreads();
  if (t < 16) {
    float s = rsum[0][t] + rsum[1][t] + rsum[2][t] + rsum[3][t];
    linv[b * NNN + m0 + t] = 1.f / s;
  }
}

// ---------------- A/B2 pre-GEMMs:  out[b][n][o] ----------------
__global__ __launch_bounds__(256) void k_ab(const float* __restrict__ f, const float* __restrict__ wl,
                                            float* __restrict__ Apre, float* __restrict__ Bpre) {
  __shared__ float fl[ND * 64];
  int t = threadIdx.x;
  int b = blockIdx.x >> 6;
  int n0 = (blockIdx.x & 63) << 6;
  for (int e = t; e < ND * 64; e += 256) {
    int d = e >> 6, c = e & 63;
    fl[e] = f[b * ND * NNN + d * NNN + n0 + c];
  }
  __syncthreads();
  int lane = t & 63;
  int w = __builtin_amdgcn_readfirstlane(t >> 6);
#pragma unroll 1
  for (int g = 0; g < 8; ++g) {
    float acc[8] = {0, 0, 0, 0, 0, 0, 0, 0};
    int p0 = w * 64 + g * 8;
    for (int d = 0; d < ND; ++d) {
      float fv = fl[d * 64 + lane];
#pragma unroll
      for (int u = 0; u < 8; ++u) {
        int p = p0 + u;
        int o = p & 127, sel = p >> 7;
        acc[u] += wl[o * 129 + sel * 64 + d] * fv;
      }
    }
#pragma unroll
    for (int u = 0; u < 8; ++u) {
      int p = p0 + u;
      int o = p & 127, sel = p >> 7;
      float* outp = sel ? Bpre : Apre;
      outp[(b * NNN + n0 + lane) * NO + o] = acc[u];
    }
  }
}

// ---------------- intra (unchanged) ----------------
__global__ __launch_bounds__(128) void k_intra(const float* __restrict__ Apre, const float* __restrict__ Bpre,
                                               const int* __restrict__ tidx, const float* __restrict__ td2,
                                               const float* __restrict__ wl, float* __restrict__ imax,
                                               float* __restrict__ imin, float* __restrict__ stats) {
  __shared__ int sidx[32 * NK];
  __shared__ float sdst[32 * NK];
  int t = threadIdx.x;
  int b = blockIdx.x >> 7;
  int n0 = (blockIdx.x & 127) << 5;
  for (int e = t; e < 32 * NK; e += 128) {
    int base = (b * NNN + n0 + (e >> 4)) * NK + (e & 15);
    sidx[e] = tidx[base];
    sdst[e] = sqrtf(td2[base]);
  }
  __syncthreads();
  int o = t;
  float w128 = wl[o * 129 + 128];
  float ssum = 0.f, ssq = 0.f;
  for (int c = 0; c < 32; ++c) {
    float a = Apre[(b * NNN + n0 + c) * NO + o];
    float mx = -3.4e38f, mn = 3.4e38f;
#pragma unroll
    for (int kx = 0; kx < NK; ++kx) {
      int id = sidx[c * NK + kx];
      float y = a + Bpre[(b * NNN + id) * NO + o] + w128 * sdst[c * NK + kx];
      mx = fmaxf(mx, y); mn = fminf(mn, y);
      ssum += y; ssq += y * y;
    }
    imax[(b * NO + o) * NNN + n0 + c] = mx;
    imin[(b * NO + o) * NNN + n0 + c] = mn;
  }
  atomicAdd(&stats[o], ssum);
  atomicAdd(&stats[NO + o], ssq);
}

// ---------------- sem: z = w_sem * (fgt[b][n][d] * linv[n])  -> [b][o][n] ----------------
__global__ __launch_bounds__(256) void k_sem(const float* __restrict__ fgt, const float* __restrict__ linv,
                                             const float* __restrict__ wsem, float* __restrict__ zsem) {
  __shared__ float fl[64 * 65];
  int t = threadIdx.x;
  int b = blockIdx.x >> 6;
  int n0 = (blockIdx.x & 63) << 6;
  for (int e = t; e < 64 * 64; e += 256) {
    int n = e >> 6, d = e & 63;
    fl[n * 65 + d] = fgt[(size_t)(b * NNN + n0 + n) * ND + d] * linv[b * NNN + n0 + n];
  }
  __syncthreads();
  int lane = t & 63;
  int ob = __builtin_amdgcn_readfirstlane((t >> 6) * 32);
#pragma unroll 1
  for (int g = 0; g < 4; ++g) {
    float acc[8] = {0, 0, 0, 0, 0, 0, 0, 0};
    for (int d = 0; d < ND; ++d) {
      float fv = fl[lane * 65 + d];
#pragma unroll
      for (int u = 0; u < 8; ++u) acc[u] += wsem[(ob + g * 8 + u) * ND + d] * fv;
    }
#pragma unroll
    for (int u = 0; u < 8; ++u)
      zsem[(b * NO + ob + g * 8 + u) * NNN + n0 + lane] = acc[u];
  }
}

// ---------------- per-channel sum/ssq (unchanged) ----------------
__global__ void k_stats(const float* __restrict__ zz, float* __restrict__ sout) {
  int o = blockIdx.x, t = threadIdx.x;
  float s = 0.f, q = 0.f;
  for (int b2 = 0; b2 < NB; ++b2) {
    const float* p = zz + (size_t)(b2 * NO + o) * NNN;
    for (int n = t; n < NNN; n += 256) { float v = p[n]; s += v; q += v * v; }
  }
#pragma unroll
  for (int off = 32; off; off >>= 1) { s += __shfl_down(s, off); q += __shfl_down(q, off); }
  __shared__ float rs[4], rq[4];
  int lane = t & 63, w = t >> 6;
  if (lane == 0) { rs[w] = s; rq[w] = q; }
  __syncthreads();
  if (t == 0) {
    sout[o]      = rs[0] + rs[1] + rs[2] + rs[3];
    sout[NO + o] = rq[0] + rq[1] + rq[2] + rq[3];
  }
}

// ---------------- finalize BN (unchanged) ----------------
__global__ void k_fin(const float* __restrict__ stats, const float* __restrict__ g,
                      const float* __restrict__ be, float cnt_inv, float* __restrict__ coef) {
  int o = threadIdx.x;
  float mean = stats[o] * cnt_inv;
  float var = stats[NO + o] * cnt_inv - mean * mean;
  var = var > 0.f ? var : 0.f;
  float a = g[o] * rsqrtf(var + BN_EPS);
  coef[o] = a;
  coef[NO + o] = be[o] - mean * a;
}

// ---------------- full (unchanged) ----------------
__global__ __launch_bounds__(256) void k_full(const float* __restrict__ imax, const float* __restrict__ imin,
                                              const float* __restrict__ zsem, const float* __restrict__ wfull,
                                              const float* __restrict__ coef, float* __restrict__ zfull) {
  __shared__ float fl[2 * NO * 64];
  int t = threadIdx.x;
  int b = blockIdx.x >> 6;
  int n0 = (blockIdx.x & 63) << 6;
  for (int e = t; e < 2 * NO * 64; e += 256) {
    int c = e >> 6, col = e & 63;
    float aa, bb, x;
    if (c < NO) {
      aa = coef[c]; bb = coef[NO + c];
      const float* src = (aa >= 0.f) ? imax : imin;
      x = src[(b * NO + c) * NNN + n0 + col];
    } else {
      int c2 = c - NO;
      aa = coef[2 * NO + c2]; bb = coef[3 * NO + c2];
      x = zsem[(b * NO + c2) * NNN + n0 + col];
    }
    float y = aa * x + bb;
    fl[e] = (y >= 0.f) ? y : NEG * y;
  }
  __syncthreads();
  int lane = t & 63;
  int ob = __builtin_amdgcn_readfirstlane((t >> 6) * 32);
#pragma unroll 1
  for (int g = 0; g < 4; ++g) {
    float acc[8] = {0, 0, 0, 0, 0, 0, 0, 0};
    for (int c = 0; c < 2 * NO; ++c) {
      float fv = fl[c * 64 + lane];
#pragma unroll
      for (int u = 0; u < 8; ++u) acc[u] += wfull[(ob + g * 8 + u) * (2 * NO) + c] * fv;
    }
#pragma unroll
    for (int u = 0; u < 8; ++u)
      zfull[(b * NO + ob + g * 8 + u) * NNN + n0 + lane] = acc[u];
  }
}

// ---------------- out = lrelu(a*z + b) ----------------
__global__ void k_out(const float* __restrict__ zfull, const float* __restrict__ coef,
                      float* __restrict__ out) {
  int gid = blockIdx.x * 256 + threadIdx.x;
  int o = (gid >> 12) & 127;
  float y = coef[o] * zfull[gid] + coef[NO + o];
  out[gid] = (y >= 0.f) ? y : NEG * y;
}

extern "C" void kernel_launch(void* const* d_in, const int* in_sizes, int n_in,
                              void* d_out, int out_size, void* d_ws, size_t ws_size,
                              hipStream_t stream) {
  (void)in_sizes; (void)n_in; (void)out_size; (void)ws_size;
  const float* f       = (const float*)d_in[0];
  const float* w_local = (const float*)d_in[1];
  const float* g_local = (const float*)d_in[2];
  const float* b_local = (const float*)d_in[3];
  const float* w_sem   = (const float*)d_in[4];
  const float* g_sem   = (const float*)d_in[5];
  const float* b_sem   = (const float*)d_in[6];
  const float* w_full  = (const float*)d_in[7];
  const float* g_full  = (const float*)d_in[8];
  const float* b_full  = (const float*)d_in[9];
  const float* wq = (const float*)d_in[10];
  const float* bq = (const float*)d_in[11];
  const float* wk = (const float*)d_in[12];
  const float* bk = (const float*)d_in[13];
  const float* wv = (const float*)d_in[14];
  const float* bv = (const float*)d_in[15];
  float* Wp = (float*)d_ws;
  u16* qb16 = (u16*)(Wp + OFF_Q);
  u16* kb16 = (u16*)(Wp + OFF_K);
  u16* vb16 = (u16*)(Wp + OFF_V);

  hipMemsetAsync(Wp + OFF_STATS, 0, 2 * NO * sizeof(float), stream);
  k_xx  <<<NB * NNN / 256, 256, 0, stream>>>(f, Wp + OFF_XX);
  k_qkv <<<dim3(NB * NNN / 64, 3), 256, 0, stream>>>(f, wq, bq, wk, bk, wv, bv, qb16, kb16, vb16);
  k_knn <<<NB * (NNN / 4), 256, 0, stream>>>(f, Wp + OFF_XX, (int*)(Wp + OFF_IDX), Wp + OFF_D2);
  k_attn<<<NB * (NNN / 16), 256, 0, stream>>>(qb16, kb16, vb16, Wp + OFF_FGT, Wp + OFF_LINV);
  k_ab  <<<NB * (NNN / 64), 256, 0, stream>>>(f, w_local, Wp + OFF_APRE, Wp + OFF_BPRE);
  k_intra<<<NB * (NNN / 32), 128, 0, stream>>>(Wp + OFF_APRE, Wp + OFF_BPRE,
                                               (const int*)(Wp + OFF_IDX), Wp + OFF_D2,
                                               w_local, Wp + OFF_IMAX, Wp + OFF_IMIN, Wp + OFF_STATS);
  k_sem <<<NB * (NNN / 64), 256, 0, stream>>>(Wp + OFF_FGT, Wp + OFF_LINV, w_sem, Wp + OFF_ZSEM);
  k_stats<<<NO, 256, 0, stream>>>(Wp + OFF_ZSEM, Wp + OFF_STATS + 2 * NO);
  k_fin <<<1, NO, 0, stream>>>(Wp + OFF_STATS,          g_local, b_local,
                               1.f / (float)(NB * NNN * NK), Wp + OFF_COEF);
  k_fin <<<1, NO, 0, stream>>>(Wp + OFF_STATS + 2 * NO, g_sem, b_sem,
                               1.f / (float)(NB * NNN), Wp + OFF_COEF + 2 * NO);
  k_full<<<NB * (NNN / 64), 256, 0, stream>>>(Wp + OFF_IMAX, Wp + OFF_IMIN, Wp + OFF_ZSEM,
                                              w_full, Wp + OFF_COEF, Wp + OFF_ZFULL);
  k_stats<<<NO, 256, 0, stream>>>(Wp + OFF_ZFULL, Wp + OFF_STATS + 4 * NO);
  k_fin <<<1, NO, 0, stream>>>(Wp + OFF_STATS + 4 * NO, g_full, b_full,
                               1.f / (float)(NB * NNN), Wp + OFF_COEF + 4 * NO);
  k_out <<<NB * NO * NNN / 256, 256, 0, stream>>>(Wp + OFF_ZFULL, Wp + OFF_COEF + 4 * NO,
                                                  (float*)d_out);
}

// Round 3
// 889.876 us; speedup vs baseline: 1.4675x; 1.0876x over previous
//
#include <hip/hip_runtime.h>
#include <math.h>

constexpr int NB = 4;      // batch
constexpr int ND = 64;     // feature dim
constexpr int NNN = 4096;  // points
constexpr int NO = 128;    // out channels
constexpr int NK = 16;     // k-nn
constexpr float NEG = 0.01f;
constexpr float BN_EPS = 1e-5f;

typedef unsigned short u16;
typedef unsigned int u32;
typedef __attribute__((ext_vector_type(8))) short short8;
typedef __attribute__((ext_vector_type(4))) float floatx4;

// workspace offsets (in floats)
constexpr int OFF_XX    = 0;
constexpr int OFF_IDX   = 16384;
constexpr int OFF_D2    = 278528;
constexpr int OFF_Q     = 540672;       // qb16 bf16 [b][n][d]
constexpr int OFF_K     = 1589248;      // kb16 bf16 [b][n][d]
constexpr int OFF_V     = 2637824;      // vb16 bf16 [b][d][n]
constexpr int OFF_FGT   = 3686400;      // fgt fp32 [b][n][d] (unnormalized)
constexpr int OFF_APRE  = 4734976;
constexpr int OFF_BPRE  = 6832128;
constexpr int OFF_IMAX  = 8929280;
constexpr int OFF_IMIN  = 11026432;
constexpr int OFF_ZSEM  = OFF_Q;
constexpr int OFF_ZFULL = OFF_V;
constexpr int OFF_STATS = 13123584;
constexpr int OFF_COEF  = 13124352;
constexpr int OFF_LINV  = 13125120;

__device__ __forceinline__ u16 f2b(float x) {       // fp32 -> bf16 RNE
  u32 u = __builtin_bit_cast(u32, x);
  u += 0x7fffu + ((u >> 16) & 1u);
  return (u16)(u >> 16);
}

// ---------------- xx[b][n] = sum_d f^2 ----------------
__global__ void k_xx(const float* __restrict__ f, float* __restrict__ xx) {
  int gid = blockIdx.x * 256 + threadIdx.x;
  int b = gid >> 12, n = gid & 4095;
  const float* fb = f + b * ND * NNN + n;
  float s = 0.f;
#pragma unroll
  for (int d = 0; d < ND; ++d) { float v = fb[d * NNN]; s += v * v; }
  xx[gid] = s;
}

// ---------------- q/k/v = W f + bias -> bf16 (q,k: [b][n][d]; v: [b][d][n]) ----------------
__global__ __launch_bounds__(256) void k_qkv(const float* __restrict__ f,
    const float* __restrict__ wq, const float* __restrict__ bq,
    const float* __restrict__ wk, const float* __restrict__ bk,
    const float* __restrict__ wv, const float* __restrict__ bv,
    u16* __restrict__ qb, u16* __restrict__ kb, u16* __restrict__ vb) {
  int sel = blockIdx.y;
  const float* W    = (sel == 0) ? wq : (sel == 1) ? wk : wv;
  const float* bias = (sel == 0) ? bq : (sel == 1) ? bk : bv;
  int t = threadIdx.x;
  int lane = t & 63;
  int og = __builtin_amdgcn_readfirstlane(t >> 6);
  int gcol = blockIdx.x * 64 + lane;
  int b = gcol >> 12, n = gcol & 4095;
  const float* fb = f + b * ND * NNN + n;
  float cv[64];
#pragma unroll
  for (int d = 0; d < ND; ++d) cv[d] = fb[d * NNN];
  float acc[16];
#pragma unroll 1
  for (int oi = 0; oi < 16; ++oi) {
    int o = og * 16 + oi;
    const float* wr = W + o * ND;
    float a = bias[o];
#pragma unroll
    for (int d = 0; d < ND; ++d) a += wr[d] * cv[d];
    acc[oi] = a;
  }
  if (sel == 2) {
#pragma unroll
    for (int oi = 0; oi < 16; ++oi)
      vb[(size_t)(b * ND + og * 16 + oi) * NNN + n] = f2b(acc[oi]);
  } else {
    short8 p0, p1;
#pragma unroll
    for (int oi = 0; oi < 8; ++oi) { p0[oi] = (short)f2b(acc[oi]); p1[oi] = (short)f2b(acc[8 + oi]); }
    u16* dst = (sel ? kb : qb) + (size_t)(b * NNN + n) * ND + og * 16;
    *(short8*)dst = p0;
    *(short8*)(dst + 8) = p1;
  }
}

// ---------------- kNN v2: 8 rows/block, wave-private tournament selection ----------------
// Phase 1 fma chain kept bit-identical to v1 (d-ascending, same contraction):
// scores must match the np reference's top-k to avoid neighbor flips.
__global__ __launch_bounds__(256, 2) void k_knn(const float* __restrict__ f, const float* __restrict__ xx,
                                                int* __restrict__ tidx, float* __restrict__ td2) {
  __shared__ float fm[ND * 8];            // [d][r] row fragments
  __shared__ float sl[4 * NNN];           // staged scores, 4 rows per pass (64 KB)
  int t = threadIdx.x;
  int lane = t & 63;
  int w = __builtin_amdgcn_readfirstlane(t >> 6);
  int b = blockIdx.x >> 9;
  int m0 = (blockIdx.x & 511) << 3;
  const float* fb = f + b * ND * NNN;
  { int e = t;     int d = e >> 3, r = e & 7; fm[e] = fb[d * NNN + m0 + r]; }
  { int e = t + 256; int d = e >> 3, r = e & 7; fm[e] = fb[d * NNN + m0 + r]; }
  __syncthreads();
  // ---- phase 1: scores acc[j][r], col = j*256+t, rows m0..m0+7 ----
  float acc[128];
#pragma unroll
  for (int i = 0; i < 128; ++i) acc[i] = 0.f;
  for (int d = 0; d < ND; ++d) {
    float4 rv0 = *(const float4*)&fm[d * 8];
    float4 rv1 = *(const float4*)&fm[d * 8 + 4];
    const float* frow = fb + d * NNN + t;
#pragma unroll
    for (int j = 0; j < 16; ++j) {
      float cv = frow[j * 256];
      acc[j * 8 + 0] += rv0.x * cv;
      acc[j * 8 + 1] += rv0.y * cv;
      acc[j * 8 + 2] += rv0.z * cv;
      acc[j * 8 + 3] += rv0.w * cv;
      acc[j * 8 + 4] += rv1.x * cv;
      acc[j * 8 + 5] += rv1.y * cv;
      acc[j * 8 + 6] += rv1.z * cv;
      acc[j * 8 + 7] += rv1.w * cv;
    }
  }
#pragma unroll
  for (int j = 0; j < 16; ++j) {
    float xv = xx[b * NNN + j * 256 + t];
#pragma unroll
    for (int r = 0; r < 8; ++r) acc[j * 8 + r] = 2.f * acc[j * 8 + r] - xv;
  }
  // ---- two staging+selection passes (rows 0-3, then 4-7) ----
#pragma unroll 1
  for (int pass = 0; pass < 2; ++pass) {
    __syncthreads();                      // LDS free (prev pass done / fm done)
#pragma unroll
    for (int j = 0; j < 16; ++j)
#pragma unroll
      for (int r = 0; r < 4; ++r)
        sl[r * NNN + j * 256 + t] = acc[j * 8 + pass * 4 + r];
    __syncthreads();
    int m = m0 + pass * 4 + w;            // this wave's row
    float xm = xx[b * NNN + m];
    // pull row into registers: vals[i] = score of col (i*64 + lane)
    float vals[64];
#pragma unroll
    for (int i = 0; i < 64; ++i) vals[i] = sl[w * NNN + i * 64 + lane];
    // group maxima (8 groups of 8)
    float gm[8];
#pragma unroll
    for (int g = 0; g < 8; ++g) {
      float m2 = vals[g * 8];
#pragma unroll
      for (int k2 = 1; k2 < 8; ++k2) m2 = fmaxf(m2, vals[g * 8 + k2]);
      gm[g] = m2;
    }
    int myidx = 0; float myd2 = 0.f;      // lanes 0..15 capture extraction kx==lane
#pragma unroll 1
    for (int kx = 0; kx < NK; ++kx) {
      // wave max value (butterfly -> all lanes)
      float lm = gm[0];
#pragma unroll
      for (int g = 1; g < 8; ++g) lm = fmaxf(lm, gm[g]);
      float Wv = lm;
#pragma unroll
      for (int off = 1; off < 64; off <<= 1) Wv = fmaxf(Wv, __shfl_xor(Wv, off));
      // locate smallest global idx holding Wv (idx = i*64 + lane)
      int loc = 0x7fffffff;
#pragma unroll
      for (int g = 0; g < 8; ++g) {
        if (gm[g] == Wv) {
#pragma unroll
          for (int k2 = 0; k2 < 8; ++k2)
            if (vals[g * 8 + k2] == Wv) loc = min(loc, (g * 8 + k2) * 64 + lane);
        }
      }
#pragma unroll
      for (int off = 1; off < 64; off <<= 1) loc = min(loc, __shfl_xor(loc, off));
      int sw = __builtin_amdgcn_readfirstlane(loc);   // uniform winner idx
      int jw = sw >> 6;                                // uniform reg slot
      int lw = sw & 63;                                // winner lane
      // mask winner + recompute its group max (uniform-branch select of slot)
#pragma unroll
      for (int g = 0; g < 8; ++g)
        if (g == (jw >> 3)) {
#pragma unroll
          for (int k2 = 0; k2 < 8; ++k2)
            if (k2 == (jw & 7))
              vals[g * 8 + k2] = (lane == lw) ? -3.0e38f : vals[g * 8 + k2];
          float m2 = vals[g * 8];
#pragma unroll
          for (int k2 = 1; k2 < 8; ++k2) m2 = fmaxf(m2, vals[g * 8 + k2]);
          gm[g] = m2;
        }
      if (lane == kx) {
        myidx = sw;
        float dd = xm - Wv;
        myd2 = dd > 0.f ? dd : 0.f;
      }
    }
    if (lane < NK) {
      int base = (b * NNN + m) * NK + lane;
      tidx[base] = myidx;
      td2[base] = myd2;
    }
  }
}

// ---------------- attention: MFMA bf16, 16 rows/block, P-chunk (16x512) in LDS ----------------
__global__ __launch_bounds__(256) void k_attn(const u16* __restrict__ qb,
                                              const u16* __restrict__ kb,
                                              const u16* __restrict__ vb,
                                              float* __restrict__ fgt,
                                              float* __restrict__ linv) {
  __shared__ __align__(16) u16 P[16 * 520];
  __shared__ float rsum[4][16];
  int t = threadIdx.x;
  int lane = t & 63;
  int w = __builtin_amdgcn_readfirstlane(t >> 6);
  int quad = lane >> 4;
  int l15 = lane & 15;
  int b = blockIdx.x >> 8;
  int m0 = (blockIdx.x & 255) << 4;
  const u16* qrow = qb + (size_t)(b * NNN + m0 + l15) * ND + quad * 8;
  short8 qa0 = *(const short8*)(qrow);
  short8 qa1 = *(const short8*)(qrow + 32);
  const u16* kbase = kb + (size_t)b * NNN * ND;
  const u16* vrow  = vb + (size_t)(b * ND + w * 16 + l15) * NNN;
  floatx4 c2 = {0.f, 0.f, 0.f, 0.f};
  float rs[4] = {0.f, 0.f, 0.f, 0.f};
#pragma unroll 1
  for (int it = 0; it < 8; ++it) {
    int nchunk = it * 512;
#pragma unroll 1
    for (int ct = 0; ct < 8; ++ct) {
      int cc0 = (w * 8 + ct) * 16;
      const u16* krow = kbase + (size_t)(nchunk + cc0 + l15) * ND + quad * 8;
      short8 kf0 = *(const short8*)(krow);
      short8 kf1 = *(const short8*)(krow + 32);
      floatx4 acc = {0.f, 0.f, 0.f, 0.f};
      acc = __builtin_amdgcn_mfma_f32_16x16x32_bf16(qa0, kf0, acc, 0, 0, 0);
      acc = __builtin_amdgcn_mfma_f32_16x16x32_bf16(qa1, kf1, acc, 0, 0, 0);
      int ccol = cc0 + l15;
#pragma unroll
      for (int r = 0; r < 4; ++r) {
        float e = __expf(acc[r] * 0.125f);
        rs[r] += e;
        P[(quad * 4 + r) * 520 + ccol] = f2b(e);
      }
    }
    __syncthreads();
    const u16* vp = vrow + nchunk + quad * 8;
#pragma unroll
    for (int kk = 0; kk < 16; ++kk) {
      short8 a2 = *(const short8*)&P[l15 * 520 + kk * 32 + quad * 8];
      short8 b2 = *(const short8*)(vp + kk * 32);
      c2 = __builtin_amdgcn_mfma_f32_16x16x32_bf16(a2, b2, c2, 0, 0, 0);
    }
    __syncthreads();
  }
#pragma unroll
  for (int r = 0; r < 4; ++r) {
    float v = rs[r];
    v += __shfl_xor(v, 1); v += __shfl_xor(v, 2);
    v += __shfl_xor(v, 4); v += __shfl_xor(v, 8);
    rs[r] = v;
  }
  if (l15 == 0) {
#pragma unroll
    for (int r = 0; r < 4; ++r) rsum[w][quad * 4 + r] = rs[r];
  }
#pragma unroll
  for (int r = 0; r < 4; ++r)
    fgt[(size_t)(b * NNN + m0 + quad * 4 + r) * ND + w * 16 + l15] = c2[r];
  __syncthreads();
  if (t < 16) {
    float s = rsum[0][t] + rsum[1][t] + rsum[2][t] + rsum[3][t];
    linv[b * NNN + m0 + t] = 1.f / s;
  }
}

// ---------------- A/B2 pre-GEMMs:  out[b][n][o] ----------------
__global__ __launch_bounds__(256) void k_ab(const float* __restrict__ f, const float* __restrict__ wl,
                                            float* __restrict__ Apre, float* __restrict__ Bpre) {
  __shared__ float fl[ND * 64];
  int t = threadIdx.x;
  int b = blockIdx.x >> 6;
  int n0 = (blockIdx.x & 63) << 6;
  for (int e = t; e < ND * 64; e += 256) {
    int d = e >> 6, c = e & 63;
    fl[e] = f[b * ND * NNN + d * NNN + n0 + c];
  }
  __syncthreads();
  int lane = t & 63;
  int w = __builtin_amdgcn_readfirstlane(t >> 6);
#pragma unroll 1
  for (int g = 0; g < 8; ++g) {
    float acc[8] = {0, 0, 0, 0, 0, 0, 0, 0};
    int p0 = w * 64 + g * 8;
    for (int d = 0; d < ND; ++d) {
      float fv = fl[d * 64 + lane];
#pragma unroll
      for (int u = 0; u < 8; ++u) {
        int p = p0 + u;
        int o = p & 127, sel = p >> 7;
        acc[u] += wl[o * 129 + sel * 64 + d] * fv;
      }
    }
#pragma unroll
    for (int u = 0; u < 8; ++u) {
      int p = p0 + u;
      int o = p & 127, sel = p >> 7;
      float* outp = sel ? Bpre : Apre;
      outp[(b * NNN + n0 + lane) * NO + o] = acc[u];
    }
  }
}

// ---------------- intra (unchanged) ----------------
__global__ __launch_bounds__(128) void k_intra(const float* __restrict__ Apre, const float* __restrict__ Bpre,
                                               const int* __restrict__ tidx, const float* __restrict__ td2,
                                               const float* __restrict__ wl, float* __restrict__ imax,
                                               float* __restrict__ imin, float* __restrict__ stats) {
  __shared__ int sidx[32 * NK];
  __shared__ float sdst[32 * NK];
  int t = threadIdx.x;
  int b = blockIdx.x >> 7;
  int n0 = (blockIdx.x & 127) << 5;
  for (int e = t; e < 32 * NK; e += 128) {
    int base = (b * NNN + n0 + (e >> 4)) * NK + (e & 15);
    sidx[e] = tidx[base];
    sdst[e] = sqrtf(td2[base]);
  }
  __syncthreads();
  int o = t;
  float w128 = wl[o * 129 + 128];
  float ssum = 0.f, ssq = 0.f;
  for (int c = 0; c < 32; ++c) {
    float a = Apre[(b * NNN + n0 + c) * NO + o];
    float mx = -3.4e38f, mn = 3.4e38f;
#pragma unroll
    for (int kx = 0; kx < NK; ++kx) {
      int id = sidx[c * NK + kx];
      float y = a + Bpre[(b * NNN + id) * NO + o] + w128 * sdst[c * NK + kx];
      mx = fmaxf(mx, y); mn = fminf(mn, y);
      ssum += y; ssq += y * y;
    }
    imax[(b * NO + o) * NNN + n0 + c] = mx;
    imin[(b * NO + o) * NNN + n0 + c] = mn;
  }
  atomicAdd(&stats[o], ssum);
  atomicAdd(&stats[NO + o], ssq);
}

// ---------------- sem: z = w_sem * (fgt[b][n][d] * linv[n])  -> [b][o][n] ----------------
__global__ __launch_bounds__(256) void k_sem(const float* __restrict__ fgt, const float* __restrict__ linv,
                                             const float* __restrict__ wsem, float* __restrict__ zsem) {
  __shared__ float fl[64 * 65];
  int t = threadIdx.x;
  int b = blockIdx.x >> 6;
  int n0 = (blockIdx.x & 63) << 6;
  for (int e = t; e < 64 * 64; e += 256) {
    int n = e >> 6, d = e & 63;
    fl[n * 65 + d] = fgt[(size_t)(b * NNN + n0 + n) * ND + d] * linv[b * NNN + n0 + n];
  }
  __syncthreads();
  int lane = t & 63;
  int ob = __builtin_amdgcn_readfirstlane((t >> 6) * 32);
#pragma unroll 1
  for (int g = 0; g < 4; ++g) {
    float acc[8] = {0, 0, 0, 0, 0, 0, 0, 0};
    for (int d = 0; d < ND; ++d) {
      float fv = fl[lane * 65 + d];
#pragma unroll
      for (int u = 0; u < 8; ++u) acc[u] += wsem[(ob + g * 8 + u) * ND + d] * fv;
    }
#pragma unroll
    for (int u = 0; u < 8; ++u)
      zsem[(b * NO + ob + g * 8 + u) * NNN + n0 + lane] = acc[u];
  }
}

// ---------------- per-channel sum/ssq (unchanged) ----------------
__global__ void k_stats(const float* __restrict__ zz, float* __restrict__ sout) {
  int o = blockIdx.x, t = threadIdx.x;
  float s = 0.f, q = 0.f;
  for (int b2 = 0; b2 < NB; ++b2) {
    const float* p = zz + (size_t)(b2 * NO + o) * NNN;
    for (int n = t; n < NNN; n += 256) { float v = p[n]; s += v; q += v * v; }
  }
#pragma unroll
  for (int off = 32; off; off >>= 1) { s += __shfl_down(s, off); q += __shfl_down(q, off); }
  __shared__ float rs[4], rq[4];
  int lane = t & 63, w = t >> 6;
  if (lane == 0) { rs[w] = s; rq[w] = q; }
  __syncthreads();
  if (t == 0) {
    sout[o]      = rs[0] + rs[1] + rs[2] + rs[3];
    sout[NO + o] = rq[0] + rq[1] + rq[2] + rq[3];
  }
}

// ---------------- finalize BN (unchanged) ----------------
__global__ void k_fin(const float* __restrict__ stats, const float* __restrict__ g,
                      const float* __restrict__ be, float cnt_inv, float* __restrict__ coef) {
  int o = threadIdx.x;
  float mean = stats[o] * cnt_inv;
  float var = stats[NO + o] * cnt_inv - mean * mean;
  var = var > 0.f ? var : 0.f;
  float a = g[o] * rsqrtf(var + BN_EPS);
  coef[o] = a;
  coef[NO + o] = be[o] - mean * a;
}

// ---------------- full (unchanged) ----------------
__global__ __launch_bounds__(256) void k_full(const float* __restrict__ imax, const float* __restrict__ imin,
                                              const float* __restrict__ zsem, const float* __restrict__ wfull,
                                              const float* __restrict__ coef, float* __restrict__ zfull) {
  __shared__ float fl[2 * NO * 64];
  int t = threadIdx.x;
  int b = blockIdx.x >> 6;
  int n0 = (blockIdx.x & 63) << 6;
  for (int e = t; e < 2 * NO * 64; e += 256) {
    int c = e >> 6, col = e & 63;
    float aa, bb, x;
    if (c < NO) {
      aa = coef[c]; bb = coef[NO + c];
      const float* src = (aa >= 0.f) ? imax : imin;
      x = src[(b * NO + c) * NNN + n0 + col];
    } else {
      int c2 = c - NO;
      aa = coef[2 * NO + c2]; bb = coef[3 * NO + c2];
      x = zsem[(b * NO + c2) * NNN + n0 + col];
    }
    float y = aa * x + bb;
    fl[e] = (y >= 0.f) ? y : NEG * y;
  }
  __syncthreads();
  int lane = t & 63;
  int ob = __builtin_amdgcn_readfirstlane((t >> 6) * 32);
#pragma unroll 1
  for (int g = 0; g < 4; ++g) {
    float acc[8] = {0, 0, 0, 0, 0, 0, 0, 0};
    for (int c = 0; c < 2 * NO; ++c) {
      float fv = fl[c * 64 + lane];
#pragma unroll
      for (int u = 0; u < 8; ++u) acc[u] += wfull[(ob + g * 8 + u) * (2 * NO) + c] * fv;
    }
#pragma unroll
    for (int u = 0; u < 8; ++u)
      zfull[(b * NO + ob + g * 8 + u) * NNN + n0 + lane] = acc[u];
  }
}

// ---------------- out = lrelu(a*z + b) ----------------
__global__ void k_out(const float* __restrict__ zfull, const float* __restrict__ coef,
                      float* __restrict__ out) {
  int gid = blockIdx.x * 256 + threadIdx.x;
  int o = (gid >> 12) & 127;
  float y = coef[o] * zfull[gid] + coef[NO + o];
  out[gid] = (y >= 0.f) ? y : NEG * y;
}

extern "C" void kernel_launch(void* const* d_in, const int* in_sizes, int n_in,
                              void* d_out, int out_size, void* d_ws, size_t ws_size,
                              hipStream_t stream) {
  (void)in_sizes; (void)n_in; (void)out_size; (void)ws_size;
  const float* f       = (const float*)d_in[0];
  const float* w_local = (const float*)d_in[1];
  const float* g_local = (const float*)d_in[2];
  const float* b_local = (const float*)d_in[3];
  const float* w_sem   = (const float*)d_in[4];
  const float* g_sem   = (const float*)d_in[5];
  const float* b_sem   = (const float*)d_in[6];
  const float* w_full  = (const float*)d_in[7];
  const float* g_full  = (const float*)d_in[8];
  const float* b_full  = (const float*)d_in[9];
  const float* wq = (const float*)d_in[10];
  const float* bq = (const float*)d_in[11];
  const float* wk = (const float*)d_in[12];
  const float* bk = (const float*)d_in[13];
  const float* wv = (const float*)d_in[14];
  const float* bv = (const float*)d_in[15];
  float* Wp = (float*)d_ws;
  u16* qb16 = (u16*)(Wp + OFF_Q);
  u16* kb16 = (u16*)(Wp + OFF_K);
  u16* vb16 = (u16*)(Wp + OFF_V);

  hipMemsetAsync(Wp + OFF_STATS, 0, 2 * NO * sizeof(float), stream);
  k_xx  <<<NB * NNN / 256, 256, 0, stream>>>(f, Wp + OFF_XX);
  k_qkv <<<dim3(NB * NNN / 64, 3), 256, 0, stream>>>(f, wq, bq, wk, bk, wv, bv, qb16, kb16, vb16);
  k_knn <<<NB * (NNN / 8), 256, 0, stream>>>(f, Wp + OFF_XX, (int*)(Wp + OFF_IDX), Wp + OFF_D2);
  k_attn<<<NB * (NNN / 16), 256, 0, stream>>>(qb16, kb16, vb16, Wp + OFF_FGT, Wp + OFF_LINV);
  k_ab  <<<NB * (NNN / 64), 256, 0, stream>>>(f, w_local, Wp + OFF_APRE, Wp + OFF_BPRE);
  k_intra<<<NB * (NNN / 32), 128, 0, stream>>>(Wp + OFF_APRE, Wp + OFF_BPRE,
                                               (const int*)(Wp + OFF_IDX), Wp + OFF_D2,
                                               w_local, Wp + OFF_IMAX, Wp + OFF_IMIN, Wp + OFF_STATS);
  k_sem <<<NB * (NNN / 64), 256, 0, stream>>>(Wp + OFF_FGT, Wp + OFF_LINV, w_sem, Wp + OFF_ZSEM);
  k_stats<<<NO, 256, 0, stream>>>(Wp + OFF_ZSEM, Wp + OFF_STATS + 2 * NO);
  k_fin <<<1, NO, 0, stream>>>(Wp + OFF_STATS,          g_local, b_local,
                               1.f / (float)(NB * NNN * NK), Wp + OFF_COEF);
  k_fin <<<1, NO, 0, stream>>>(Wp + OFF_STATS + 2 * NO, g_sem, b_sem,
                               1.f / (float)(NB * NNN), Wp + OFF_COEF + 2 * NO);
  k_full<<<NB * (NNN / 64), 256, 0, stream>>>(Wp + OFF_IMAX, Wp + OFF_IMIN, Wp + OFF_ZSEM,
                                              w_full, Wp + OFF_COEF, Wp + OFF_ZFULL);
  k_stats<<<NO, 256, 0, stream>>>(Wp + OFF_ZFULL, Wp + OFF_STATS + 4 * NO);
  k_fin <<<1, NO, 0, stream>>>(Wp + OFF_STATS + 4 * NO, g_full, b_full,
                               1.f / (float)(NB * NNN), Wp + OFF_COEF + 4 * NO);
  k_out <<<NB * NO * NNN / 256, 256, 0, stream>>>(Wp + OFF_ZFULL, Wp + OFF_COEF + 4 * NO,
                                                  (float*)d_out);
}

// Round 4
// 780.964 us; speedup vs baseline: 1.6721x; 1.1395x over previous
//
#include <hip/hip_runtime.h>
#include <math.h>

constexpr int NB = 4;      // batch
constexpr int ND = 64;     // feature dim
constexpr int NNN = 4096;  // points
constexpr int NO = 128;    // out channels
constexpr int NK = 16;     // k-nn
constexpr float NEG = 0.01f;
constexpr float BN_EPS = 1e-5f;

typedef unsigned short u16;
typedef unsigned int u32;
typedef __attribute__((ext_vector_type(8))) short short8;
typedef __attribute__((ext_vector_type(4))) float floatx4;

// workspace offsets (in floats)
constexpr int OFF_XX    = 0;
constexpr int OFF_IDX   = 16384;
constexpr int OFF_D2    = 278528;
constexpr int OFF_Q     = 540672;       // qb16 bf16 [b][n][d]
constexpr int OFF_K     = 1589248;      // kb16 bf16 [b][n][d]
constexpr int OFF_V     = 2637824;      // vb16 bf16 [b][d][n]
constexpr int OFF_FGT   = 3686400;      // fgt fp32 [b][n][d] (unnormalized)
constexpr int OFF_APRE  = 4734976;
constexpr int OFF_BPRE  = 6832128;
constexpr int OFF_IMAX  = 8929280;
constexpr int OFF_IMIN  = 11026432;
constexpr int OFF_ZSEM  = OFF_Q;
constexpr int OFF_ZFULL = OFF_V;
constexpr int OFF_STATS = 13123584;
constexpr int OFF_COEF  = 13124352;
constexpr int OFF_LINV  = 13125120;

__device__ __forceinline__ u16 f2b(float x) {       // fp32 -> bf16 RNE
  u32 u = __builtin_bit_cast(u32, x);
  u += 0x7fffu + ((u >> 16) & 1u);
  return (u16)(u >> 16);
}

// ---------------- xx[b][n] = sum_d f^2 ----------------
__global__ void k_xx(const float* __restrict__ f, float* __restrict__ xx) {
  int gid = blockIdx.x * 256 + threadIdx.x;
  int b = gid >> 12, n = gid & 4095;
  const float* fb = f + b * ND * NNN + n;
  float s = 0.f;
#pragma unroll
  for (int d = 0; d < ND; ++d) { float v = fb[d * NNN]; s += v * v; }
  xx[gid] = s;
}

// ---------------- q/k/v = W f + bias -> bf16 (q,k: [b][n][d]; v: [b][d][n]) ----------------
__global__ __launch_bounds__(256) void k_qkv(const float* __restrict__ f,
    const float* __restrict__ wq, const float* __restrict__ bq,
    const float* __restrict__ wk, const float* __restrict__ bk,
    const float* __restrict__ wv, const float* __restrict__ bv,
    u16* __restrict__ qb, u16* __restrict__ kb, u16* __restrict__ vb) {
  int sel = blockIdx.y;
  const float* W    = (sel == 0) ? wq : (sel == 1) ? wk : wv;
  const float* bias = (sel == 0) ? bq : (sel == 1) ? bk : bv;
  int t = threadIdx.x;
  int lane = t & 63;
  int og = __builtin_amdgcn_readfirstlane(t >> 6);
  int gcol = blockIdx.x * 64 + lane;
  int b = gcol >> 12, n = gcol & 4095;
  const float* fb = f + b * ND * NNN + n;
  float cv[64];
#pragma unroll
  for (int d = 0; d < ND; ++d) cv[d] = fb[d * NNN];
  float acc[16];
#pragma unroll 1
  for (int oi = 0; oi < 16; ++oi) {
    int o = og * 16 + oi;
    const float* wr = W + o * ND;
    float a = bias[o];
#pragma unroll
    for (int d = 0; d < ND; ++d) a += wr[d] * cv[d];
    acc[oi] = a;
  }
  if (sel == 2) {
#pragma unroll
    for (int oi = 0; oi < 16; ++oi)
      vb[(size_t)(b * ND + og * 16 + oi) * NNN + n] = f2b(acc[oi]);
  } else {
    short8 p0, p1;
#pragma unroll
    for (int oi = 0; oi < 8; ++oi) { p0[oi] = (short)f2b(acc[oi]); p1[oi] = (short)f2b(acc[8 + oi]); }
    u16* dst = (sel ? kb : qb) + (size_t)(b * NNN + n) * ND + og * 16;
    *(short8*)dst = p0;
    *(short8*)(dst + 8) = p1;
  }
}

// ---------------- kNN v3: 8 rows/block, wave-private tournament, NO dynamic
// private-array indexing (pass loop fully unrolled -> acc stays in VGPRs) ----------------
__global__ __launch_bounds__(256, 2) void k_knn(const float* __restrict__ f, const float* __restrict__ xx,
                                                int* __restrict__ tidx, float* __restrict__ td2) {
  __shared__ float fm[ND * 8];            // [d][r] row fragments
  __shared__ float sl[4 * NNN];           // staged scores, 4 rows per pass (64 KB)
  int t = threadIdx.x;
  int lane = t & 63;
  int w = __builtin_amdgcn_readfirstlane(t >> 6);
  int b = blockIdx.x >> 9;
  int m0 = (blockIdx.x & 511) << 3;
  const float* fb = f + b * ND * NNN;
  { int e = t;       int d = e >> 3, r = e & 7; fm[e] = fb[d * NNN + m0 + r]; }
  { int e = t + 256; int d = e >> 3, r = e & 7; fm[e] = fb[d * NNN + m0 + r]; }
  __syncthreads();
  // ---- phase 1: scores acc[j][r], col = j*256+t, rows m0..m0+7 ----
  float acc[128];
#pragma unroll
  for (int i = 0; i < 128; ++i) acc[i] = 0.f;
  for (int d = 0; d < ND; ++d) {
    float4 rv0 = *(const float4*)&fm[d * 8];
    float4 rv1 = *(const float4*)&fm[d * 8 + 4];
    const float* frow = fb + d * NNN + t;
#pragma unroll
    for (int j = 0; j < 16; ++j) {
      float cv = frow[j * 256];
      acc[j * 8 + 0] += rv0.x * cv;
      acc[j * 8 + 1] += rv0.y * cv;
      acc[j * 8 + 2] += rv0.z * cv;
      acc[j * 8 + 3] += rv0.w * cv;
      acc[j * 8 + 4] += rv1.x * cv;
      acc[j * 8 + 5] += rv1.y * cv;
      acc[j * 8 + 6] += rv1.z * cv;
      acc[j * 8 + 7] += rv1.w * cv;
    }
  }
#pragma unroll
  for (int j = 0; j < 16; ++j) {
    float xv = xx[b * NNN + j * 256 + t];
#pragma unroll
    for (int r = 0; r < 8; ++r) acc[j * 8 + r] = 2.f * acc[j * 8 + r] - xv;
  }
  // ---- two staging+selection passes (FULLY UNROLLED: static acc indices) ----
#pragma unroll
  for (int pass = 0; pass < 2; ++pass) {
    __syncthreads();                      // LDS free (prev pass done / fm done)
#pragma unroll
    for (int j = 0; j < 16; ++j)
#pragma unroll
      for (int r = 0; r < 4; ++r)
        sl[r * NNN + j * 256 + t] = acc[j * 8 + pass * 4 + r];
    __syncthreads();
    int m = m0 + pass * 4 + w;            // this wave's row
    float xm = xx[b * NNN + m];
    // pull row into registers: vals[i] = score of col (i*64 + lane)
    float vals[64];
#pragma unroll
    for (int i = 0; i < 64; ++i) vals[i] = sl[w * NNN + i * 64 + lane];
    // group maxima (8 groups of 8)
    float gm[8];
#pragma unroll
    for (int g = 0; g < 8; ++g) {
      float m2 = vals[g * 8];
#pragma unroll
      for (int k2 = 1; k2 < 8; ++k2) m2 = fmaxf(m2, vals[g * 8 + k2]);
      gm[g] = m2;
    }
    int myidx = 0; float myd2 = 0.f;      // lanes 0..15 capture extraction kx==lane
#pragma unroll 1
    for (int kx = 0; kx < NK; ++kx) {
      // wave max value (butterfly -> all lanes)
      float lm = gm[0];
#pragma unroll
      for (int g = 1; g < 8; ++g) lm = fmaxf(lm, gm[g]);
      float Wv = lm;
#pragma unroll
      for (int off = 1; off < 64; off <<= 1) Wv = fmaxf(Wv, __shfl_xor(Wv, off));
      // locate smallest global idx holding Wv (idx = i*64 + lane)
      int loc = 0x7fffffff;
#pragma unroll
      for (int g = 0; g < 8; ++g) {
        if (gm[g] == Wv) {
#pragma unroll
          for (int k2 = 0; k2 < 8; ++k2)
            if (vals[g * 8 + k2] == Wv) loc = min(loc, (g * 8 + k2) * 64 + lane);
        }
      }
#pragma unroll
      for (int off = 1; off < 64; off <<= 1) loc = min(loc, __shfl_xor(loc, off));
      int sw = __builtin_amdgcn_readfirstlane(loc);   // uniform winner idx
      int jw = sw >> 6;                                // uniform reg slot
      int lw = sw & 63;                                // winner lane
      // mask winner + recompute its group max (uniform-branch select of slot)
#pragma unroll
      for (int g = 0; g < 8; ++g)
        if (g == (jw >> 3)) {
#pragma unroll
          for (int k2 = 0; k2 < 8; ++k2)
            if (k2 == (jw & 7))
              vals[g * 8 + k2] = (lane == lw) ? -3.0e38f : vals[g * 8 + k2];
          float m2 = vals[g * 8];
#pragma unroll
          for (int k2 = 1; k2 < 8; ++k2) m2 = fmaxf(m2, vals[g * 8 + k2]);
          gm[g] = m2;
        }
      if (lane == kx) {
        myidx = sw;
        float dd = xm - Wv;
        myd2 = dd > 0.f ? dd : 0.f;
      }
    }
    if (lane < NK) {
      int base = (b * NNN + m) * NK + lane;
      tidx[base] = myidx;
      td2[base] = myd2;
    }
  }
}

// ---------------- attention: MFMA bf16, 16 rows/block, P-chunk (16x512) in LDS ----------------
__global__ __launch_bounds__(256) void k_attn(const u16* __restrict__ qb,
                                              const u16* __restrict__ kb,
                                              const u16* __restrict__ vb,
                                              float* __restrict__ fgt,
                                              float* __restrict__ linv) {
  __shared__ __align__(16) u16 P[16 * 520];
  __shared__ float rsum[4][16];
  int t = threadIdx.x;
  int lane = t & 63;
  int w = __builtin_amdgcn_readfirstlane(t >> 6);
  int quad = lane >> 4;
  int l15 = lane & 15;
  int b = blockIdx.x >> 8;
  int m0 = (blockIdx.x & 255) << 4;
  const u16* qrow = qb + (size_t)(b * NNN + m0 + l15) * ND + quad * 8;
  short8 qa0 = *(const short8*)(qrow);
  short8 qa1 = *(const short8*)(qrow + 32);
  const u16* kbase = kb + (size_t)b * NNN * ND;
  const u16* vrow  = vb + (size_t)(b * ND + w * 16 + l15) * NNN;
  floatx4 c2 = {0.f, 0.f, 0.f, 0.f};
  float rs[4] = {0.f, 0.f, 0.f, 0.f};
#pragma unroll 1
  for (int it = 0; it < 8; ++it) {
    int nchunk = it * 512;
#pragma unroll 1
    for (int ct = 0; ct < 8; ++ct) {
      int cc0 = (w * 8 + ct) * 16;
      const u16* krow = kbase + (size_t)(nchunk + cc0 + l15) * ND + quad * 8;
      short8 kf0 = *(const short8*)(krow);
      short8 kf1 = *(const short8*)(krow + 32);
      floatx4 acc = {0.f, 0.f, 0.f, 0.f};
      acc = __builtin_amdgcn_mfma_f32_16x16x32_bf16(qa0, kf0, acc, 0, 0, 0);
      acc = __builtin_amdgcn_mfma_f32_16x16x32_bf16(qa1, kf1, acc, 0, 0, 0);
      int ccol = cc0 + l15;
#pragma unroll
      for (int r = 0; r < 4; ++r) {
        float e = __expf(acc[r] * 0.125f);
        rs[r] += e;
        P[(quad * 4 + r) * 520 + ccol] = f2b(e);
      }
    }
    __syncthreads();
    const u16* vp = vrow + nchunk + quad * 8;
#pragma unroll
    for (int kk = 0; kk < 16; ++kk) {
      short8 a2 = *(const short8*)&P[l15 * 520 + kk * 32 + quad * 8];
      short8 b2 = *(const short8*)(vp + kk * 32);
      c2 = __builtin_amdgcn_mfma_f32_16x16x32_bf16(a2, b2, c2, 0, 0, 0);
    }
    __syncthreads();
  }
#pragma unroll
  for (int r = 0; r < 4; ++r) {
    float v = rs[r];
    v += __shfl_xor(v, 1); v += __shfl_xor(v, 2);
    v += __shfl_xor(v, 4); v += __shfl_xor(v, 8);
    rs[r] = v;
  }
  if (l15 == 0) {
#pragma unroll
    for (int r = 0; r < 4; ++r) rsum[w][quad * 4 + r] = rs[r];
  }
#pragma unroll
  for (int r = 0; r < 4; ++r)
    fgt[(size_t)(b * NNN + m0 + quad * 4 + r) * ND + w * 16 + l15] = c2[r];
  __syncthreads();
  if (t < 16) {
    float s = rsum[0][t] + rsum[1][t] + rsum[2][t] + rsum[3][t];
    linv[b * NNN + m0 + t] = 1.f / s;
  }
}

// ---------------- A/B2 pre-GEMMs:  out[b][n][o] ----------------
__global__ __launch_bounds__(256) void k_ab(const float* __restrict__ f, const float* __restrict__ wl,
                                            float* __restrict__ Apre, float* __restrict__ Bpre) {
  __shared__ float fl[ND * 64];
  int t = threadIdx.x;
  int b = blockIdx.x >> 6;
  int n0 = (blockIdx.x & 63) << 6;
  for (int e = t; e < ND * 64; e += 256) {
    int d = e >> 6, c = e & 63;
    fl[e] = f[b * ND * NNN + d * NNN + n0 + c];
  }
  __syncthreads();
  int lane = t & 63;
  int w = __builtin_amdgcn_readfirstlane(t >> 6);
#pragma unroll 1
  for (int g = 0; g < 8; ++g) {
    float acc[8] = {0, 0, 0, 0, 0, 0, 0, 0};
    int p0 = w * 64 + g * 8;
    for (int d = 0; d < ND; ++d) {
      float fv = fl[d * 64 + lane];
#pragma unroll
      for (int u = 0; u < 8; ++u) {
        int p = p0 + u;
        int o = p & 127, sel = p >> 7;
        acc[u] += wl[o * 129 + sel * 64 + d] * fv;
      }
    }
#pragma unroll
    for (int u = 0; u < 8; ++u) {
      int p = p0 + u;
      int o = p & 127, sel = p >> 7;
      float* outp = sel ? Bpre : Apre;
      outp[(b * NNN + n0 + lane) * NO + o] = acc[u];
    }
  }
}

// ---------------- intra (unchanged) ----------------
__global__ __launch_bounds__(128) void k_intra(const float* __restrict__ Apre, const float* __restrict__ Bpre,
                                               const int* __restrict__ tidx, const float* __restrict__ td2,
                                               const float* __restrict__ wl, float* __restrict__ imax,
                                               float* __restrict__ imin, float* __restrict__ stats) {
  __shared__ int sidx[32 * NK];
  __shared__ float sdst[32 * NK];
  int t = threadIdx.x;
  int b = blockIdx.x >> 7;
  int n0 = (blockIdx.x & 127) << 5;
  for (int e = t; e < 32 * NK; e += 128) {
    int base = (b * NNN + n0 + (e >> 4)) * NK + (e & 15);
    sidx[e] = tidx[base];
    sdst[e] = sqrtf(td2[base]);
  }
  __syncthreads();
  int o = t;
  float w128 = wl[o * 129 + 128];
  float ssum = 0.f, ssq = 0.f;
  for (int c = 0; c < 32; ++c) {
    float a = Apre[(b * NNN + n0 + c) * NO + o];
    float mx = -3.4e38f, mn = 3.4e38f;
#pragma unroll
    for (int kx = 0; kx < NK; ++kx) {
      int id = sidx[c * NK + kx];
      float y = a + Bpre[(b * NNN + id) * NO + o] + w128 * sdst[c * NK + kx];
      mx = fmaxf(mx, y); mn = fminf(mn, y);
      ssum += y; ssq += y * y;
    }
    imax[(b * NO + o) * NNN + n0 + c] = mx;
    imin[(b * NO + o) * NNN + n0 + c] = mn;
  }
  atomicAdd(&stats[o], ssum);
  atomicAdd(&stats[NO + o], ssq);
}

// ---------------- sem: z = w_sem * (fgt[b][n][d] * linv[n])  -> [b][o][n] ----------------
__global__ __launch_bounds__(256) void k_sem(const float* __restrict__ fgt, const float* __restrict__ linv,
                                             const float* __restrict__ wsem, float* __restrict__ zsem) {
  __shared__ float fl[64 * 65];
  int t = threadIdx.x;
  int b = blockIdx.x >> 6;
  int n0 = (blockIdx.x & 63) << 6;
  for (int e = t; e < 64 * 64; e += 256) {
    int n = e >> 6, d = e & 63;
    fl[n * 65 + d] = fgt[(size_t)(b * NNN + n0 + n) * ND + d] * linv[b * NNN + n0 + n];
  }
  __syncthreads();
  int lane = t & 63;
  int ob = __builtin_amdgcn_readfirstlane((t >> 6) * 32);
#pragma unroll 1
  for (int g = 0; g < 4; ++g) {
    float acc[8] = {0, 0, 0, 0, 0, 0, 0, 0};
    for (int d = 0; d < ND; ++d) {
      float fv = fl[lane * 65 + d];
#pragma unroll
      for (int u = 0; u < 8; ++u) acc[u] += wsem[(ob + g * 8 + u) * ND + d] * fv;
    }
#pragma unroll
    for (int u = 0; u < 8; ++u)
      zsem[(b * NO + ob + g * 8 + u) * NNN + n0 + lane] = acc[u];
  }
}

// ---------------- per-channel sum/ssq (unchanged) ----------------
__global__ void k_stats(const float* __restrict__ zz, float* __restrict__ sout) {
  int o = blockIdx.x, t = threadIdx.x;
  float s = 0.f, q = 0.f;
  for (int b2 = 0; b2 < NB; ++b2) {
    const float* p = zz + (size_t)(b2 * NO + o) * NNN;
    for (int n = t; n < NNN; n += 256) { float v = p[n]; s += v; q += v * v; }
  }
#pragma unroll
  for (int off = 32; off; off >>= 1) { s += __shfl_down(s, off); q += __shfl_down(q, off); }
  __shared__ float rs[4], rq[4];
  int lane = t & 63, w = t >> 6;
  if (lane == 0) { rs[w] = s; rq[w] = q; }
  __syncthreads();
  if (t == 0) {
    sout[o]      = rs[0] + rs[1] + rs[2] + rs[3];
    sout[NO + o] = rq[0] + rq[1] + rq[2] + rq[3];
  }
}

// ---------------- finalize BN (unchanged) ----------------
__global__ void k_fin(const float* __restrict__ stats, const float* __restrict__ g,
                      const float* __restrict__ be, float cnt_inv, float* __restrict__ coef) {
  int o = threadIdx.x;
  float mean = stats[o] * cnt_inv;
  float var = stats[NO + o] * cnt_inv - mean * mean;
  var = var > 0.f ? var : 0.f;
  float a = g[o] * rsqrtf(var + BN_EPS);
  coef[o] = a;
  coef[NO + o] = be[o] - mean * a;
}

// ---------------- full (unchanged) ----------------
__global__ __launch_bounds__(256) void k_full(const float* __restrict__ imax, const float* __restrict__ imin,
                                              const float* __restrict__ zsem, const float* __restrict__ wfull,
                                              const float* __restrict__ coef, float* __restrict__ zfull) {
  __shared__ float fl[2 * NO * 64];
  int t = threadIdx.x;
  int b = blockIdx.x >> 6;
  int n0 = (blockIdx.x & 63) << 6;
  for (int e = t; e < 2 * NO * 64; e += 256) {
    int c = e >> 6, col = e & 63;
    float aa, bb, x;
    if (c < NO) {
      aa = coef[c]; bb = coef[NO + c];
      const float* src = (aa >= 0.f) ? imax : imin;
      x = src[(b * NO + c) * NNN + n0 + col];
    } else {
      int c2 = c - NO;
      aa = coef[2 * NO + c2]; bb = coef[3 * NO + c2];
      x = zsem[(b * NO + c2) * NNN + n0 + col];
    }
    float y = aa * x + bb;
    fl[e] = (y >= 0.f) ? y : NEG * y;
  }
  __syncthreads();
  int lane = t & 63;
  int ob = __builtin_amdgcn_readfirstlane((t >> 6) * 32);
#pragma unroll 1
  for (int g = 0; g < 4; ++g) {
    float acc[8] = {0, 0, 0, 0, 0, 0, 0, 0};
    for (int c = 0; c < 2 * NO; ++c) {
      float fv = fl[c * 64 + lane];
#pragma unroll
      for (int u = 0; u < 8; ++u) acc[u] += wfull[(ob + g * 8 + u) * (2 * NO) + c] * fv;
    }
#pragma unroll
    for (int u = 0; u < 8; ++u)
      zfull[(b * NO + ob + g * 8 + u) * NNN + n0 + lane] = acc[u];
  }
}

// ---------------- out = lrelu(a*z + b) ----------------
__global__ void k_out(const float* __restrict__ zfull, const float* __restrict__ coef,
                      float* __restrict__ out) {
  int gid = blockIdx.x * 256 + threadIdx.x;
  int o = (gid >> 12) & 127;
  float y = coef[o] * zfull[gid] + coef[NO + o];
  out[gid] = (y >= 0.f) ? y : NEG * y;
}

extern "C" void kernel_launch(void* const* d_in, const int* in_sizes, int n_in,
                              void* d_out, int out_size, void* d_ws, size_t ws_size,
                              hipStream_t stream) {
  (void)in_sizes; (void)n_in; (void)out_size; (void)ws_size;
  const float* f       = (const float*)d_in[0];
  const float* w_local = (const float*)d_in[1];
  const float* g_local = (const float*)d_in[2];
  const float* b_local = (const float*)d_in[3];
  const float* w_sem   = (const float*)d_in[4];
  const float* g_sem   = (const float*)d_in[5];
  const float* b_sem   = (const float*)d_in[6];
  const float* w_full  = (const float*)d_in[7];
  const float* g_full  = (const float*)d_in[8];
  const float* b_full  = (const float*)d_in[9];
  const float* wq = (const float*)d_in[10];
  const float* bq = (const float*)d_in[11];
  const float* wk = (const float*)d_in[12];
  const float* bk = (const float*)d_in[13];
  const float* wv = (const float*)d_in[14];
  const float* bv = (const float*)d_in[15];
  float* Wp = (float*)d_ws;
  u16* qb16 = (u16*)(Wp + OFF_Q);
  u16* kb16 = (u16*)(Wp + OFF_K);
  u16* vb16 = (u16*)(Wp + OFF_V);

  hipMemsetAsync(Wp + OFF_STATS, 0, 2 * NO * sizeof(float), stream);
  k_xx  <<<NB * NNN / 256, 256, 0, stream>>>(f, Wp + OFF_XX);
  k_qkv <<<dim3(NB * NNN / 64, 3), 256, 0, stream>>>(f, wq, bq, wk, bk, wv, bv, qb16, kb16, vb16);
  k_knn <<<NB * (NNN / 8), 256, 0, stream>>>(f, Wp + OFF_XX, (int*)(Wp + OFF_IDX), Wp + OFF_D2);
  k_attn<<<NB * (NNN / 16), 256, 0, stream>>>(qb16, kb16, vb16, Wp + OFF_FGT, Wp + OFF_LINV);
  k_ab  <<<NB * (NNN / 64), 256, 0, stream>>>(f, w_local, Wp + OFF_APRE, Wp + OFF_BPRE);
  k_intra<<<NB * (NNN / 32), 128, 0, stream>>>(Wp + OFF_APRE, Wp + OFF_BPRE,
                                               (const int*)(Wp + OFF_IDX), Wp + OFF_D2,
                                               w_local, Wp + OFF_IMAX, Wp + OFF_IMIN, Wp + OFF_STATS);
  k_sem <<<NB * (NNN / 64), 256, 0, stream>>>(Wp + OFF_FGT, Wp + OFF_LINV, w_sem, Wp + OFF_ZSEM);
  k_stats<<<NO, 256, 0, stream>>>(Wp + OFF_ZSEM, Wp + OFF_STATS + 2 * NO);
  k_fin <<<1, NO, 0, stream>>>(Wp + OFF_STATS,          g_local, b_local,
                               1.f / (float)(NB * NNN * NK), Wp + OFF_COEF);
  k_fin <<<1, NO, 0, stream>>>(Wp + OFF_STATS + 2 * NO, g_sem, b_sem,
                               1.f / (float)(NB * NNN), Wp + OFF_COEF + 2 * NO);
  k_full<<<NB * (NNN / 64), 256, 0, stream>>>(Wp + OFF_IMAX, Wp + OFF_IMIN, Wp + OFF_ZSEM,
                                              w_full, Wp + OFF_COEF, Wp + OFF_ZFULL);
  k_stats<<<NO, 256, 0, stream>>>(Wp + OFF_ZFULL, Wp + OFF_STATS + 4 * NO);
  k_fin <<<1, NO, 0, stream>>>(Wp + OFF_STATS + 4 * NO, g_full, b_full,
                               1.f / (float)(NB * NNN), Wp + OFF_COEF + 4 * NO);
  k_out <<<NB * NO * NNN / 256, 256, 0, stream>>>(Wp + OFF_ZFULL, Wp + OFF_COEF + 4 * NO,
                                                  (float*)d_out);
}

// Round 5
// 743.582 us; speedup vs baseline: 1.7562x; 1.0503x over previous
//
#include <hip/hip_runtime.h>
#include <math.h>

constexpr int NB = 4;      // batch
constexpr int ND = 64;     // feature dim
constexpr int NNN = 4096;  // points
constexpr int NO = 128;    // out channels
constexpr int NK = 16;     // k-nn
constexpr float NEG = 0.01f;
constexpr float BN_EPS = 1e-5f;

typedef unsigned short u16;
typedef unsigned int u32;
typedef __attribute__((ext_vector_type(8))) short short8;
typedef __attribute__((ext_vector_type(4))) float floatx4;

// workspace offsets (in floats)
constexpr int OFF_XX    = 0;
constexpr int OFF_IDX   = 16384;
constexpr int OFF_D2    = 278528;
constexpr int OFF_Q     = 540672;       // qb16 bf16 [b][n][d]
constexpr int OFF_K     = 1589248;      // kb16 bf16 [b][n][d]
constexpr int OFF_V     = 2637824;      // vb16 bf16 [b][d][n]
constexpr int OFF_FGT   = 3686400;      // fgt fp32 [b][n][d] (unnormalized)
constexpr int OFF_APRE  = 4734976;
constexpr int OFF_BPRE  = 6832128;
constexpr int OFF_IMAX  = 8929280;
constexpr int OFF_IMIN  = 11026432;
constexpr int OFF_ZSEM  = OFF_Q;
constexpr int OFF_ZFULL = OFF_V;
constexpr int OFF_STATS = 13123584;
constexpr int OFF_COEF  = 13124352;
constexpr int OFF_LINV  = 13125120;

__device__ __forceinline__ u16 f2b(float x) {       // fp32 -> bf16 RNE
  u32 u = __builtin_bit_cast(u32, x);
  u += 0x7fffu + ((u >> 16) & 1u);
  return (u16)(u >> 16);
}

// ---------------- xx[b][n] = sum_d f^2 ----------------
__global__ void k_xx(const float* __restrict__ f, float* __restrict__ xx) {
  int gid = blockIdx.x * 256 + threadIdx.x;
  int b = gid >> 12, n = gid & 4095;
  const float* fb = f + b * ND * NNN + n;
  float s = 0.f;
#pragma unroll
  for (int d = 0; d < ND; ++d) { float v = fb[d * NNN]; s += v * v; }
  xx[gid] = s;
}

// ---------------- q/k/v = W f + bias -> bf16 (q,k: [b][n][d]; v: [b][d][n]) ----------------
__global__ __launch_bounds__(256) void k_qkv(const float* __restrict__ f,
    const float* __restrict__ wq, const float* __restrict__ bq,
    const float* __restrict__ wk, const float* __restrict__ bk,
    const float* __restrict__ wv, const float* __restrict__ bv,
    u16* __restrict__ qb, u16* __restrict__ kb, u16* __restrict__ vb) {
  int sel = blockIdx.y;
  const float* W    = (sel == 0) ? wq : (sel == 1) ? wk : wv;
  const float* bias = (sel == 0) ? bq : (sel == 1) ? bk : bv;
  int t = threadIdx.x;
  int lane = t & 63;
  int og = __builtin_amdgcn_readfirstlane(t >> 6);
  int gcol = blockIdx.x * 64 + lane;
  int b = gcol >> 12, n = gcol & 4095;
  const float* fb = f + b * ND * NNN + n;
  float cv[64];
#pragma unroll
  for (int d = 0; d < ND; ++d) cv[d] = fb[d * NNN];
  float acc[16];
#pragma unroll 1
  for (int oi = 0; oi < 16; ++oi) {
    int o = og * 16 + oi;
    const float* wr = W + o * ND;
    float a = bias[o];
#pragma unroll
    for (int d = 0; d < ND; ++d) a += wr[d] * cv[d];
    acc[oi] = a;
  }
  if (sel == 2) {
#pragma unroll
    for (int oi = 0; oi < 16; ++oi)
      vb[(size_t)(b * ND + og * 16 + oi) * NNN + n] = f2b(acc[oi]);
  } else {
    short8 p0, p1;
#pragma unroll
    for (int oi = 0; oi < 8; ++oi) { p0[oi] = (short)f2b(acc[oi]); p1[oi] = (short)f2b(acc[8 + oi]); }
    u16* dst = (sel ? kb : qb) + (size_t)(b * NNN + n) * ND + og * 16;
    *(short8*)dst = p0;
    *(short8*)(dst + 8) = p1;
  }
}

// ---------------- kNN v4: 8 rows/block, col-halves of 2048 (acc stays in VGPRs),
// float4 loads, 4-rows-per-stint LDS staging (32KB -> 4 blocks/CU),
// per-half top-16 tournament + stable 16+16 merge (exact jax tie semantics) ----------------
__global__ __launch_bounds__(256, 4) void k_knn(const float* __restrict__ f, const float* __restrict__ xx,
                                                int* __restrict__ tidx, float* __restrict__ td2) {
  __shared__ __align__(16) float fm[ND * 8];   // [d][r] row fragments (2 KB)
  __shared__ __align__(16) float sl[4 * 2048]; // 4 rows x 2048 cols (32 KB)
  int t = threadIdx.x;
  int lane = t & 63;
  int w = __builtin_amdgcn_readfirstlane(t >> 6);
  int b = blockIdx.x >> 9;
  int m0 = (blockIdx.x & 511) << 3;
  const float* fb = f + b * ND * NNN;
  { int e = t;       int d = e >> 3, r = e & 7; fm[e] = fb[d * NNN + m0 + r]; }
  { int e = t + 256; int d = e >> 3, r = e & 7; fm[e] = fb[d * NNN + m0 + r]; }
  __syncthreads();
  float lv[2][2];                         // [half][stint] extraction value (rank = lane 0..15)
  int   li[2][2];                         // global col index
#pragma unroll
  for (int h = 0; h < 2; ++h) {
    // ---- phase 1 for this col-half: acc[jj*32 + c*8 + r], col = h*2048 + jj*1024 + 4t + c ----
    float acc[64];
#pragma unroll
    for (int i = 0; i < 64; ++i) acc[i] = 0.f;
    for (int d = 0; d < ND; ++d) {
      const float* frow = fb + d * NNN + h * 2048 + 4 * t;
      float4 v0 = *(const float4*)(frow);
      float4 v1 = *(const float4*)(frow + 1024);
      float4 r0 = *(const float4*)&fm[d * 8];
      float4 r1 = *(const float4*)&fm[d * 8 + 4];
      float va0[4] = {v0.x, v0.y, v0.z, v0.w};
      float va1[4] = {v1.x, v1.y, v1.z, v1.w};
      float rr[8]  = {r0.x, r0.y, r0.z, r0.w, r1.x, r1.y, r1.z, r1.w};
#pragma unroll
      for (int c2 = 0; c2 < 4; ++c2)
#pragma unroll
        for (int r = 0; r < 8; ++r) {
          acc[c2 * 8 + r]      += va0[c2] * rr[r];
          acc[32 + c2 * 8 + r] += va1[c2] * rr[r];
        }
    }
    {
      const float* xrow = xx + b * NNN + h * 2048 + 4 * t;
      float4 x0 = *(const float4*)(xrow);
      float4 x1 = *(const float4*)(xrow + 1024);
      float xa0[4] = {x0.x, x0.y, x0.z, x0.w};
      float xa1[4] = {x1.x, x1.y, x1.z, x1.w};
#pragma unroll
      for (int c2 = 0; c2 < 4; ++c2)
#pragma unroll
        for (int r = 0; r < 8; ++r) {
          acc[c2 * 8 + r]      = 2.f * acc[c2 * 8 + r]      - xa0[c2];
          acc[32 + c2 * 8 + r] = 2.f * acc[32 + c2 * 8 + r] - xa1[c2];
        }
    }
    // ---- two stints: stage rows s*4..s*4+3, wave w selects row s*4+w ----
#pragma unroll
    for (int s = 0; s < 2; ++s) {
      __syncthreads();                    // prev stint/half reads done
#pragma unroll
      for (int r4 = 0; r4 < 4; ++r4) {
        int r = s * 4 + r4;
#pragma unroll
        for (int jj = 0; jj < 2; ++jj) {
          float4 w4;
          w4.x = acc[jj * 32 + 0 * 8 + r];
          w4.y = acc[jj * 32 + 1 * 8 + r];
          w4.z = acc[jj * 32 + 2 * 8 + r];
          w4.w = acc[jj * 32 + 3 * 8 + r];
          *(float4*)&sl[r4 * 2048 + jj * 1024 + 4 * t] = w4;
        }
      }
      __syncthreads();
      // selection: 32 vals/lane over 2048 cols, groups of 4
      float vals[32];
#pragma unroll
      for (int i = 0; i < 32; ++i) vals[i] = sl[w * 2048 + i * 64 + lane];
      float gm[8];
#pragma unroll
      for (int g = 0; g < 8; ++g)
        gm[g] = fmaxf(fmaxf(vals[g * 4], vals[g * 4 + 1]), fmaxf(vals[g * 4 + 2], vals[g * 4 + 3]));
#pragma unroll 1
      for (int kx = 0; kx < NK; ++kx) {
        float lm = gm[0];
#pragma unroll
        for (int g = 1; g < 8; ++g) lm = fmaxf(lm, gm[g]);
        float Wv = lm;
#pragma unroll
        for (int off = 1; off < 64; off <<= 1) Wv = fmaxf(Wv, __shfl_xor(Wv, off));
        int loc = 0x7fffffff;
#pragma unroll
        for (int g = 0; g < 8; ++g) {
          if (gm[g] == Wv) {
#pragma unroll
            for (int k2 = 0; k2 < 4; ++k2)
              if (vals[g * 4 + k2] == Wv) loc = min(loc, (g * 4 + k2) * 64 + lane);
          }
        }
#pragma unroll
        for (int off = 1; off < 64; off <<= 1) loc = min(loc, __shfl_xor(loc, off));
        int sw = __builtin_amdgcn_readfirstlane(loc);
        int jw = sw >> 6;                 // uniform reg slot 0..31
        int lw = sw & 63;                 // winner lane
#pragma unroll
        for (int g = 0; g < 8; ++g)
          if (g == (jw >> 2)) {
#pragma unroll
            for (int k2 = 0; k2 < 4; ++k2)
              if (k2 == (jw & 3))
                vals[g * 4 + k2] = (lane == lw) ? -3.0e38f : vals[g * 4 + k2];
            gm[g] = fmaxf(fmaxf(vals[g * 4], vals[g * 4 + 1]), fmaxf(vals[g * 4 + 2], vals[g * 4 + 3]));
          }
        if (lane == kx) { lv[h][s] = Wv; li[h][s] = h * 2048 + sw; }
      }
    }
  }
  // ---- stable merge of half-0 / half-1 top-16 lists (all h0 idx < h1 idx) ----
#pragma unroll
  for (int s = 0; s < 2; ++s) {
    int m = m0 + s * 4 + w;
    float xm = xx[b * NNN + m];
    float a   = lv[0][s]; int ai  = li[0][s];
    float bb2 = lv[1][s]; int bi2 = li[1][s];
    int cntB = 0, cntA = 0;
#pragma unroll
    for (int j = 0; j < 16; ++j) {
      float bj = __shfl(bb2, j);
      cntB += (bj > a) ? 1 : 0;
      float aj = __shfl(a, j);
      cntA += (aj >= bb2) ? 1 : 0;
    }
    if (lane < 16) {
      int base = (b * NNN + m) * NK;
      int rA = lane + cntB;
      int rB = lane + cntA;
      if (rA < NK) {
        float dd = xm - a;
        tidx[base + rA] = ai;
        td2[base + rA] = dd > 0.f ? dd : 0.f;
      }
      if (rB < NK) {
        float dd = xm - bb2;
        tidx[base + rB] = bi2;
        td2[base + rB] = dd > 0.f ? dd : 0.f;
      }
    }
  }
}

// ---------------- attention: MFMA bf16, 16 rows/block, P-chunk (16x512) in LDS ----------------
__global__ __launch_bounds__(256) void k_attn(const u16* __restrict__ qb,
                                              const u16* __restrict__ kb,
                                              const u16* __restrict__ vb,
                                              float* __restrict__ fgt,
                                              float* __restrict__ linv) {
  __shared__ __align__(16) u16 P[16 * 520];
  __shared__ float rsum[4][16];
  int t = threadIdx.x;
  int lane = t & 63;
  int w = __builtin_amdgcn_readfirstlane(t >> 6);
  int quad = lane >> 4;
  int l15 = lane & 15;
  int b = blockIdx.x >> 8;
  int m0 = (blockIdx.x & 255) << 4;
  const u16* qrow = qb + (size_t)(b * NNN + m0 + l15) * ND + quad * 8;
  short8 qa0 = *(const short8*)(qrow);
  short8 qa1 = *(const short8*)(qrow + 32);
  const u16* kbase = kb + (size_t)b * NNN * ND;
  const u16* vrow  = vb + (size_t)(b * ND + w * 16 + l15) * NNN;
  floatx4 c2 = {0.f, 0.f, 0.f, 0.f};
  float rs[4] = {0.f, 0.f, 0.f, 0.f};
#pragma unroll 1
  for (int it = 0; it < 8; ++it) {
    int nchunk = it * 512;
#pragma unroll 1
    for (int ct = 0; ct < 8; ++ct) {
      int cc0 = (w * 8 + ct) * 16;
      const u16* krow = kbase + (size_t)(nchunk + cc0 + l15) * ND + quad * 8;
      short8 kf0 = *(const short8*)(krow);
      short8 kf1 = *(const short8*)(krow + 32);
      floatx4 acc = {0.f, 0.f, 0.f, 0.f};
      acc = __builtin_amdgcn_mfma_f32_16x16x32_bf16(qa0, kf0, acc, 0, 0, 0);
      acc = __builtin_amdgcn_mfma_f32_16x16x32_bf16(qa1, kf1, acc, 0, 0, 0);
      int ccol = cc0 + l15;
#pragma unroll
      for (int r = 0; r < 4; ++r) {
        float e = __expf(acc[r] * 0.125f);
        rs[r] += e;
        P[(quad * 4 + r) * 520 + ccol] = f2b(e);
      }
    }
    __syncthreads();
    const u16* vp = vrow + nchunk + quad * 8;
#pragma unroll
    for (int kk = 0; kk < 16; ++kk) {
      short8 a2 = *(const short8*)&P[l15 * 520 + kk * 32 + quad * 8];
      short8 b2 = *(const short8*)(vp + kk * 32);
      c2 = __builtin_amdgcn_mfma_f32_16x16x32_bf16(a2, b2, c2, 0, 0, 0);
    }
    __syncthreads();
  }
#pragma unroll
  for (int r = 0; r < 4; ++r) {
    float v = rs[r];
    v += __shfl_xor(v, 1); v += __shfl_xor(v, 2);
    v += __shfl_xor(v, 4); v += __shfl_xor(v, 8);
    rs[r] = v;
  }
  if (l15 == 0) {
#pragma unroll
    for (int r = 0; r < 4; ++r) rsum[w][quad * 4 + r] = rs[r];
  }
#pragma unroll
  for (int r = 0; r < 4; ++r)
    fgt[(size_t)(b * NNN + m0 + quad * 4 + r) * ND + w * 16 + l15] = c2[r];
  __syncthreads();
  if (t < 16) {
    float s = rsum[0][t] + rsum[1][t] + rsum[2][t] + rsum[3][t];
    linv[b * NNN + m0 + t] = 1.f / s;
  }
}

// ---------------- A/B2 pre-GEMMs:  out[b][n][o] ----------------
__global__ __launch_bounds__(256) void k_ab(const float* __restrict__ f, const float* __restrict__ wl,
                                            float* __restrict__ Apre, float* __restrict__ Bpre) {
  __shared__ float fl[ND * 64];
  int t = threadIdx.x;
  int b = blockIdx.x >> 6;
  int n0 = (blockIdx.x & 63) << 6;
  for (int e = t; e < ND * 64; e += 256) {
    int d = e >> 6, c = e & 63;
    fl[e] = f[b * ND * NNN + d * NNN + n0 + c];
  }
  __syncthreads();
  int lane = t & 63;
  int w = __builtin_amdgcn_readfirstlane(t >> 6);
#pragma unroll 1
  for (int g = 0; g < 8; ++g) {
    float acc[8] = {0, 0, 0, 0, 0, 0, 0, 0};
    int p0 = w * 64 + g * 8;
    for (int d = 0; d < ND; ++d) {
      float fv = fl[d * 64 + lane];
#pragma unroll
      for (int u = 0; u < 8; ++u) {
        int p = p0 + u;
        int o = p & 127, sel = p >> 7;
        acc[u] += wl[o * 129 + sel * 64 + d] * fv;
      }
    }
#pragma unroll
    for (int u = 0; u < 8; ++u) {
      int p = p0 + u;
      int o = p & 127, sel = p >> 7;
      float* outp = sel ? Bpre : Apre;
      outp[(b * NNN + n0 + lane) * NO + o] = acc[u];
    }
  }
}

// ---------------- intra (unchanged) ----------------
__global__ __launch_bounds__(128) void k_intra(const float* __restrict__ Apre, const float* __restrict__ Bpre,
                                               const int* __restrict__ tidx, const float* __restrict__ td2,
                                               const float* __restrict__ wl, float* __restrict__ imax,
                                               float* __restrict__ imin, float* __restrict__ stats) {
  __shared__ int sidx[32 * NK];
  __shared__ float sdst[32 * NK];
  int t = threadIdx.x;
  int b = blockIdx.x >> 7;
  int n0 = (blockIdx.x & 127) << 5;
  for (int e = t; e < 32 * NK; e += 128) {
    int base = (b * NNN + n0 + (e >> 4)) * NK + (e & 15);
    sidx[e] = tidx[base];
    sdst[e] = sqrtf(td2[base]);
  }
  __syncthreads();
  int o = t;
  float w128 = wl[o * 129 + 128];
  float ssum = 0.f, ssq = 0.f;
  for (int c = 0; c < 32; ++c) {
    float a = Apre[(b * NNN + n0 + c) * NO + o];
    float mx = -3.4e38f, mn = 3.4e38f;
#pragma unroll
    for (int kx = 0; kx < NK; ++kx) {
      int id = sidx[c * NK + kx];
      float y = a + Bpre[(b * NNN + id) * NO + o] + w128 * sdst[c * NK + kx];
      mx = fmaxf(mx, y); mn = fminf(mn, y);
      ssum += y; ssq += y * y;
    }
    imax[(b * NO + o) * NNN + n0 + c] = mx;
    imin[(b * NO + o) * NNN + n0 + c] = mn;
  }
  atomicAdd(&stats[o], ssum);
  atomicAdd(&stats[NO + o], ssq);
}

// ---------------- sem: z = w_sem * (fgt[b][n][d] * linv[n])  -> [b][o][n] ----------------
__global__ __launch_bounds__(256) void k_sem(const float* __restrict__ fgt, const float* __restrict__ linv,
                                             const float* __restrict__ wsem, float* __restrict__ zsem) {
  __shared__ float fl[64 * 65];
  int t = threadIdx.x;
  int b = blockIdx.x >> 6;
  int n0 = (blockIdx.x & 63) << 6;
  for (int e = t; e < 64 * 64; e += 256) {
    int n = e >> 6, d = e & 63;
    fl[n * 65 + d] = fgt[(size_t)(b * NNN + n0 + n) * ND + d] * linv[b * NNN + n0 + n];
  }
  __syncthreads();
  int lane = t & 63;
  int ob = __builtin_amdgcn_readfirstlane((t >> 6) * 32);
#pragma unroll 1
  for (int g = 0; g < 4; ++g) {
    float acc[8] = {0, 0, 0, 0, 0, 0, 0, 0};
    for (int d = 0; d < ND; ++d) {
      float fv = fl[lane * 65 + d];
#pragma unroll
      for (int u = 0; u < 8; ++u) acc[u] += wsem[(ob + g * 8 + u) * ND + d] * fv;
    }
#pragma unroll
    for (int u = 0; u < 8; ++u)
      zsem[(b * NO + ob + g * 8 + u) * NNN + n0 + lane] = acc[u];
  }
}

// ---------------- per-channel sum/ssq (unchanged) ----------------
__global__ void k_stats(const float* __restrict__ zz, float* __restrict__ sout) {
  int o = blockIdx.x, t = threadIdx.x;
  float s = 0.f, q = 0.f;
  for (int b2 = 0; b2 < NB; ++b2) {
    const float* p = zz + (size_t)(b2 * NO + o) * NNN;
    for (int n = t; n < NNN; n += 256) { float v = p[n]; s += v; q += v * v; }
  }
#pragma unroll
  for (int off = 32; off; off >>= 1) { s += __shfl_down(s, off); q += __shfl_down(q, off); }
  __shared__ float rs[4], rq[4];
  int lane = t & 63, w = t >> 6;
  if (lane == 0) { rs[w] = s; rq[w] = q; }
  __syncthreads();
  if (t == 0) {
    sout[o]      = rs[0] + rs[1] + rs[2] + rs[3];
    sout[NO + o] = rq[0] + rq[1] + rq[2] + rq[3];
  }
}

// ---------------- finalize BN (unchanged) ----------------
__global__ void k_fin(const float* __restrict__ stats, const float* __restrict__ g,
                      const float* __restrict__ be, float cnt_inv, float* __restrict__ coef) {
  int o = threadIdx.x;
  float mean = stats[o] * cnt_inv;
  float var = stats[NO + o] * cnt_inv - mean * mean;
  var = var > 0.f ? var : 0.f;
  float a = g[o] * rsqrtf(var + BN_EPS);
  coef[o] = a;
  coef[NO + o] = be[o] - mean * a;
}

// ---------------- full (unchanged) ----------------
__global__ __launch_bounds__(256) void k_full(const float* __restrict__ imax, const float* __restrict__ imin,
                                              const float* __restrict__ zsem, const float* __restrict__ wfull,
                                              const float* __restrict__ coef, float* __restrict__ zfull) {
  __shared__ float fl[2 * NO * 64];
  int t = threadIdx.x;
  int b = blockIdx.x >> 6;
  int n0 = (blockIdx.x & 63) << 6;
  for (int e = t; e < 2 * NO * 64; e += 256) {
    int c = e >> 6, col = e & 63;
    float aa, bb, x;
    if (c < NO) {
      aa = coef[c]; bb = coef[NO + c];
      const float* src = (aa >= 0.f) ? imax : imin;
      x = src[(b * NO + c) * NNN + n0 + col];
    } else {
      int c2 = c - NO;
      aa = coef[2 * NO + c2]; bb = coef[3 * NO + c2];
      x = zsem[(b * NO + c2) * NNN + n0 + col];
    }
    float y = aa * x + bb;
    fl[e] = (y >= 0.f) ? y : NEG * y;
  }
  __syncthreads();
  int lane = t & 63;
  int ob = __builtin_amdgcn_readfirstlane((t >> 6) * 32);
#pragma unroll 1
  for (int g = 0; g < 4; ++g) {
    float acc[8] = {0, 0, 0, 0, 0, 0, 0, 0};
    for (int c = 0; c < 2 * NO; ++c) {
      float fv = fl[c * 64 + lane];
#pragma unroll
      for (int u = 0; u < 8; ++u) acc[u] += wfull[(ob + g * 8 + u) * (2 * NO) + c] * fv;
    }
#pragma unroll
    for (int u = 0; u < 8; ++u)
      zfull[(b * NO + ob + g * 8 + u) * NNN + n0 + lane] = acc[u];
  }
}

// ---------------- out = lrelu(a*z + b) ----------------
__global__ void k_out(const float* __restrict__ zfull, const float* __restrict__ coef,
                      float* __restrict__ out) {
  int gid = blockIdx.x * 256 + threadIdx.x;
  int o = (gid >> 12) & 127;
  float y = coef[o] * zfull[gid] + coef[NO + o];
  out[gid] = (y >= 0.f) ? y : NEG * y;
}

extern "C" void kernel_launch(void* const* d_in, const int* in_sizes, int n_in,
                              void* d_out, int out_size, void* d_ws, size_t ws_size,
                              hipStream_t stream) {
  (void)in_sizes; (void)n_in; (void)out_size; (void)ws_size;
  const float* f       = (const float*)d_in[0];
  const float* w_local = (const float*)d_in[1];
  const float* g_local = (const float*)d_in[2];
  const float* b_local = (const float*)d_in[3];
  const float* w_sem   = (const float*)d_in[4];
  const float* g_sem   = (const float*)d_in[5];
  const float* b_sem   = (const float*)d_in[6];
  const float* w_full  = (const float*)d_in[7];
  const float* g_full  = (const float*)d_in[8];
  const float* b_full  = (const float*)d_in[9];
  const float* wq = (const float*)d_in[10];
  const float* bq = (const float*)d_in[11];
  const float* wk = (const float*)d_in[12];
  const float* bk = (const float*)d_in[13];
  const float* wv = (const float*)d_in[14];
  const float* bv = (const float*)d_in[15];
  float* Wp = (float*)d_ws;
  u16* qb16 = (u16*)(Wp + OFF_Q);
  u16* kb16 = (u16*)(Wp + OFF_K);
  u16* vb16 = (u16*)(Wp + OFF_V);

  hipMemsetAsync(Wp + OFF_STATS, 0, 2 * NO * sizeof(float), stream);
  k_xx  <<<NB * NNN / 256, 256, 0, stream>>>(f, Wp + OFF_XX);
  k_qkv <<<dim3(NB * NNN / 64, 3), 256, 0, stream>>>(f, wq, bq, wk, bk, wv, bv, qb16, kb16, vb16);
  k_knn <<<NB * (NNN / 8), 256, 0, stream>>>(f, Wp + OFF_XX, (int*)(Wp + OFF_IDX), Wp + OFF_D2);
  k_attn<<<NB * (NNN / 16), 256, 0, stream>>>(qb16, kb16, vb16, Wp + OFF_FGT, Wp + OFF_LINV);
  k_ab  <<<NB * (NNN / 64), 256, 0, stream>>>(f, w_local, Wp + OFF_APRE, Wp + OFF_BPRE);
  k_intra<<<NB * (NNN / 32), 128, 0, stream>>>(Wp + OFF_APRE, Wp + OFF_BPRE,
                                               (const int*)(Wp + OFF_IDX), Wp + OFF_D2,
                                               w_local, Wp + OFF_IMAX, Wp + OFF_IMIN, Wp + OFF_STATS);
  k_sem <<<NB * (NNN / 64), 256, 0, stream>>>(Wp + OFF_FGT, Wp + OFF_LINV, w_sem, Wp + OFF_ZSEM);
  k_stats<<<NO, 256, 0, stream>>>(Wp + OFF_ZSEM, Wp + OFF_STATS + 2 * NO);
  k_fin <<<1, NO, 0, stream>>>(Wp + OFF_STATS,          g_local, b_local,
                               1.f / (float)(NB * NNN * NK), Wp + OFF_COEF);
  k_fin <<<1, NO, 0, stream>>>(Wp + OFF_STATS + 2 * NO, g_sem, b_sem,
                               1.f / (float)(NB * NNN), Wp + OFF_COEF + 2 * NO);
  k_full<<<NB * (NNN / 64), 256, 0, stream>>>(Wp + OFF_IMAX, Wp + OFF_IMIN, Wp + OFF_ZSEM,
                                              w_full, Wp + OFF_COEF, Wp + OFF_ZFULL);
  k_stats<<<NO, 256, 0, stream>>>(Wp + OFF_ZFULL, Wp + OFF_STATS + 4 * NO);
  k_fin <<<1, NO, 0, stream>>>(Wp + OFF_STATS + 4 * NO, g_full, b_full,
                               1.f / (float)(NB * NNN), Wp + OFF_COEF + 4 * NO);
  k_out <<<NB * NO * NNN / 256, 256, 0, stream>>>(Wp + OFF_ZFULL, Wp + OFF_COEF + 4 * NO,
                                                  (float*)d_out);
}

// Round 6
// 736.180 us; speedup vs baseline: 1.7738x; 1.0101x over previous
//
#include <hip/hip_runtime.h>
#include <math.h>

constexpr int NB = 4;      // batch
constexpr int ND = 64;     // feature dim
constexpr int NNN = 4096;  // points
constexpr int NO = 128;    // out channels
constexpr int NK = 16;     // k-nn
constexpr float NEG = 0.01f;
constexpr float BN_EPS = 1e-5f;

typedef unsigned short u16;
typedef unsigned int u32;
typedef __attribute__((ext_vector_type(8))) short short8;
typedef __attribute__((ext_vector_type(4))) float floatx4;

// workspace offsets (in floats)
constexpr int OFF_XX    = 0;
constexpr int OFF_IDX   = 16384;
constexpr int OFF_D2    = 278528;
constexpr int OFF_Q     = 540672;       // qb16 bf16 [b][n][d]
constexpr int OFF_K     = 1589248;      // kb16 bf16 [b][n][d]
constexpr int OFF_V     = 2637824;      // vb16 bf16 [b][d][n]
constexpr int OFF_FGT   = 3686400;      // fgt fp32 [b][n][d] (unnormalized)
constexpr int OFF_APRE  = 4734976;
constexpr int OFF_BPRE  = 6832128;
constexpr int OFF_IMAX  = 8929280;
constexpr int OFF_IMIN  = 11026432;
constexpr int OFF_ZSEM  = OFF_Q;
constexpr int OFF_ZFULL = OFF_V;
constexpr int OFF_STATS = 13123584;
constexpr int OFF_COEF  = 13124352;
constexpr int OFF_LINV  = 13125120;

__device__ __forceinline__ u16 f2b(float x) {       // fp32 -> bf16 RNE
  u32 u = __builtin_bit_cast(u32, x);
  u += 0x7fffu + ((u >> 16) & 1u);
  return (u16)(u >> 16);
}

// ---- (value,index) argmax fold step via DPP (in-row, all source lanes valid) ----
// comparator: larger value wins; tie -> smaller index (jax top_k stable semantics)
template <int CTRL>
__device__ __forceinline__ void red_step_dpp(float& v, int& i) {
  int vb = __builtin_bit_cast(int, v);
  int vs = __builtin_amdgcn_update_dpp(vb, vb, CTRL, 0xF, 0xF, false);
  int is = __builtin_amdgcn_update_dpp(i, i, CTRL, 0xF, 0xF, false);
  float vf = __builtin_bit_cast(float, vs);
  bool take = (vf > v) || (vf == v && is < i);
  v = take ? vf : v;
  i = take ? is : i;
}
__device__ __forceinline__ void red_step_shfl(float& v, int& i, int m) {
  float vf = __shfl_xor(v, m);
  int is = __shfl_xor(i, m);
  bool take = (vf > v) || (vf == v && is < i);
  v = take ? vf : v;
  i = take ? is : i;
}

// ---------------- xx[b][n] = sum_d f^2 ----------------
__global__ void k_xx(const float* __restrict__ f, float* __restrict__ xx) {
  int gid = blockIdx.x * 256 + threadIdx.x;
  int b = gid >> 12, n = gid & 4095;
  const float* fb = f + b * ND * NNN + n;
  float s = 0.f;
#pragma unroll
  for (int d = 0; d < ND; ++d) { float v = fb[d * NNN]; s += v * v; }
  xx[gid] = s;
}

// ---------------- q/k/v = W f + bias -> bf16 (q,k: [b][n][d]; v: [b][d][n]) ----------------
__global__ __launch_bounds__(256) void k_qkv(const float* __restrict__ f,
    const float* __restrict__ wq, const float* __restrict__ bq,
    const float* __restrict__ wk, const float* __restrict__ bk,
    const float* __restrict__ wv, const float* __restrict__ bv,
    u16* __restrict__ qb, u16* __restrict__ kb, u16* __restrict__ vb) {
  int sel = blockIdx.y;
  const float* W    = (sel == 0) ? wq : (sel == 1) ? wk : wv;
  const float* bias = (sel == 0) ? bq : (sel == 1) ? bk : bv;
  int t = threadIdx.x;
  int lane = t & 63;
  int og = __builtin_amdgcn_readfirstlane(t >> 6);
  int gcol = blockIdx.x * 64 + lane;
  int b = gcol >> 12, n = gcol & 4095;
  const float* fb = f + b * ND * NNN + n;
  float cv[64];
#pragma unroll
  for (int d = 0; d < ND; ++d) cv[d] = fb[d * NNN];
  float acc[16];
#pragma unroll 1
  for (int oi = 0; oi < 16; ++oi) {
    int o = og * 16 + oi;
    const float* wr = W + o * ND;
    float a = bias[o];
#pragma unroll
    for (int d = 0; d < ND; ++d) a += wr[d] * cv[d];
    acc[oi] = a;
  }
  if (sel == 2) {
#pragma unroll
    for (int oi = 0; oi < 16; ++oi)
      vb[(size_t)(b * ND + og * 16 + oi) * NNN + n] = f2b(acc[oi]);
  } else {
    short8 p0, p1;
#pragma unroll
    for (int oi = 0; oi < 8; ++oi) { p0[oi] = (short)f2b(acc[oi]); p1[oi] = (short)f2b(acc[8 + oi]); }
    u16* dst = (sel ? kb : qb) + (size_t)(b * NNN + n) * ND + og * 16;
    *(short8*)dst = p0;
    *(short8*)(dst + 8) = p1;
  }
}

// ---------------- kNN v5: 8 rows/block, col-halves of 2048, float4 loads,
// DPP (value,index)-pair argmax extraction (no shfl butcherfly chains, no locate loop) ----------------
__global__ __launch_bounds__(256, 4) void k_knn(const float* __restrict__ f, const float* __restrict__ xx,
                                                int* __restrict__ tidx, float* __restrict__ td2) {
  __shared__ __align__(16) float fm[ND * 8];   // [d][r] row fragments (2 KB)
  __shared__ __align__(16) float sl[4 * 2048]; // 4 rows x 2048 cols (32 KB)
  int t = threadIdx.x;
  int lane = t & 63;
  int w = __builtin_amdgcn_readfirstlane(t >> 6);
  int b = blockIdx.x >> 9;
  int m0 = (blockIdx.x & 511) << 3;
  const float* fb = f + b * ND * NNN;
  { int e = t;       int d = e >> 3, r = e & 7; fm[e] = fb[d * NNN + m0 + r]; }
  { int e = t + 256; int d = e >> 3, r = e & 7; fm[e] = fb[d * NNN + m0 + r]; }
  __syncthreads();
  float lv[2][2];                         // [half][stint] extraction value (rank = lane 0..15)
  int   li[2][2];                         // global col index
#pragma unroll
  for (int h = 0; h < 2; ++h) {
    // ---- phase 1 (bit-identical fma chain): acc[jj*32 + c*8 + r], col = h*2048 + jj*1024 + 4t + c ----
    float acc[64];
#pragma unroll
    for (int i = 0; i < 64; ++i) acc[i] = 0.f;
    for (int d = 0; d < ND; ++d) {
      const float* frow = fb + d * NNN + h * 2048 + 4 * t;
      float4 v0 = *(const float4*)(frow);
      float4 v1 = *(const float4*)(frow + 1024);
      float4 r0 = *(const float4*)&fm[d * 8];
      float4 r1 = *(const float4*)&fm[d * 8 + 4];
      float va0[4] = {v0.x, v0.y, v0.z, v0.w};
      float va1[4] = {v1.x, v1.y, v1.z, v1.w};
      float rr[8]  = {r0.x, r0.y, r0.z, r0.w, r1.x, r1.y, r1.z, r1.w};
#pragma unroll
      for (int c2 = 0; c2 < 4; ++c2)
#pragma unroll
        for (int r = 0; r < 8; ++r) {
          acc[c2 * 8 + r]      += va0[c2] * rr[r];
          acc[32 + c2 * 8 + r] += va1[c2] * rr[r];
        }
    }
    {
      const float* xrow = xx + b * NNN + h * 2048 + 4 * t;
      float4 x0 = *(const float4*)(xrow);
      float4 x1 = *(const float4*)(xrow + 1024);
      float xa0[4] = {x0.x, x0.y, x0.z, x0.w};
      float xa1[4] = {x1.x, x1.y, x1.z, x1.w};
#pragma unroll
      for (int c2 = 0; c2 < 4; ++c2)
#pragma unroll
        for (int r = 0; r < 8; ++r) {
          acc[c2 * 8 + r]      = 2.f * acc[c2 * 8 + r]      - xa0[c2];
          acc[32 + c2 * 8 + r] = 2.f * acc[32 + c2 * 8 + r] - xa1[c2];
        }
    }
    // ---- two stints: stage rows s*4..s*4+3, wave w selects row s*4+w ----
#pragma unroll
    for (int s = 0; s < 2; ++s) {
      __syncthreads();                    // prev stint/half reads done
#pragma unroll
      for (int r4 = 0; r4 < 4; ++r4) {
        int r = s * 4 + r4;
#pragma unroll
        for (int jj = 0; jj < 2; ++jj) {
          float4 w4;
          w4.x = acc[jj * 32 + 0 * 8 + r];
          w4.y = acc[jj * 32 + 1 * 8 + r];
          w4.z = acc[jj * 32 + 2 * 8 + r];
          w4.w = acc[jj * 32 + 3 * 8 + r];
          *(float4*)&sl[r4 * 2048 + jj * 1024 + 4 * t] = w4;
        }
      }
      __syncthreads();
      // selection: 32 vals/lane over 2048 cols (col = slot*64 + lane), groups of 4
      float vals[32];
#pragma unroll
      for (int i = 0; i < 32; ++i) vals[i] = sl[w * 2048 + i * 64 + lane];
      float gv[8]; int gi[8];
#pragma unroll
      for (int g = 0; g < 8; ++g) {       // within-lane col increases with slot -> strict > keeps min col
        float v0 = vals[g * 4]; int b0 = (g * 4) * 64 + lane;
#pragma unroll
        for (int k2 = 1; k2 < 4; ++k2) {
          float vk = vals[g * 4 + k2]; int ik = (g * 4 + k2) * 64 + lane;
          bool tk = vk > v0; v0 = tk ? vk : v0; b0 = tk ? ik : b0;
        }
        gv[g] = v0; gi[g] = b0;
      }
#pragma unroll 1
      for (int kx = 0; kx < NK; ++kx) {
        float lv2 = gv[0]; int li2 = gi[0];
#pragma unroll
        for (int g = 1; g < 8; ++g) {     // gi increases with g within a lane -> strict >
          bool tk = gv[g] > lv2; lv2 = tk ? gv[g] : lv2; li2 = tk ? gi[g] : li2;
        }
        // wave argmax: 4 DPP in-row levels + 2 cross-row shfl levels
        red_step_dpp<0xB1>(lv2, li2);     // quad_perm [1,0,3,2]  (xor1)
        red_step_dpp<0x4E>(lv2, li2);     // quad_perm [2,3,0,1]  (xor2)
        red_step_dpp<0x124>(lv2, li2);    // row_ror:4
        red_step_dpp<0x128>(lv2, li2);    // row_ror:8 (= xor8 in row of 16)
        red_step_shfl(lv2, li2, 16);
        red_step_shfl(lv2, li2, 32);
        int wi = __builtin_amdgcn_readfirstlane(li2);  // uniform winner col (in half)
        int jw = wi >> 6;                  // slot 0..31
        int lw = wi & 63;                  // owning lane
#pragma unroll
        for (int g = 0; g < 8; ++g)
          if (g == (jw >> 2)) {            // uniform compare -> scalar branch
#pragma unroll
            for (int k2 = 0; k2 < 4; ++k2)
              if (k2 == (jw & 3))
                vals[g * 4 + k2] = (lane == lw) ? -3.0e38f : vals[g * 4 + k2];
            float v0 = vals[g * 4]; int b0 = (g * 4) * 64 + lane;
#pragma unroll
            for (int k2 = 1; k2 < 4; ++k2) {
              float vk = vals[g * 4 + k2]; int ik = (g * 4 + k2) * 64 + lane;
              bool tk = vk > v0; v0 = tk ? vk : v0; b0 = tk ? ik : b0;
            }
            gv[g] = v0; gi[g] = b0;
          }
        if (lane == kx) { lv[h][s] = lv2; li[h][s] = h * 2048 + wi; }
      }
    }
  }
  // ---- stable merge of half-0 / half-1 top-16 lists (all h0 idx < h1 idx) ----
#pragma unroll
  for (int s = 0; s < 2; ++s) {
    int m = m0 + s * 4 + w;
    float xm = xx[b * NNN + m];
    float a   = lv[0][s]; int ai  = li[0][s];
    float bb2 = lv[1][s]; int bi2 = li[1][s];
    int cntB = 0, cntA = 0;
#pragma unroll
    for (int j = 0; j < 16; ++j) {
      float bj = __shfl(bb2, j);
      cntB += (bj > a) ? 1 : 0;
      float aj = __shfl(a, j);
      cntA += (aj >= bb2) ? 1 : 0;
    }
    if (lane < 16) {
      int base = (b * NNN + m) * NK;
      int rA = lane + cntB;
      int rB = lane + cntA;
      if (rA < NK) {
        float dd = xm - a;
        tidx[base + rA] = ai;
        td2[base + rA] = dd > 0.f ? dd : 0.f;
      }
      if (rB < NK) {
        float dd = xm - bb2;
        tidx[base + rB] = bi2;
        td2[base + rB] = dd > 0.f ? dd : 0.f;
      }
    }
  }
}

// ---------------- attention: MFMA bf16, 16 rows/block, P-chunk (16x512) in LDS ----------------
__global__ __launch_bounds__(256) void k_attn(const u16* __restrict__ qb,
                                              const u16* __restrict__ kb,
                                              const u16* __restrict__ vb,
                                              float* __restrict__ fgt,
                                              float* __restrict__ linv) {
  __shared__ __align__(16) u16 P[16 * 520];
  __shared__ float rsum[4][16];
  int t = threadIdx.x;
  int lane = t & 63;
  int w = __builtin_amdgcn_readfirstlane(t >> 6);
  int quad = lane >> 4;
  int l15 = lane & 15;
  int b = blockIdx.x >> 8;
  int m0 = (blockIdx.x & 255) << 4;
  const u16* qrow = qb + (size_t)(b * NNN + m0 + l15) * ND + quad * 8;
  short8 qa0 = *(const short8*)(qrow);
  short8 qa1 = *(const short8*)(qrow + 32);
  const u16* kbase = kb + (size_t)b * NNN * ND;
  const u16* vrow  = vb + (size_t)(b * ND + w * 16 + l15) * NNN;
  floatx4 c2 = {0.f, 0.f, 0.f, 0.f};
  float rs[4] = {0.f, 0.f, 0.f, 0.f};
#pragma unroll 1
  for (int it = 0; it < 8; ++it) {
    int nchunk = it * 512;
#pragma unroll 1
    for (int ct = 0; ct < 8; ++ct) {
      int cc0 = (w * 8 + ct) * 16;
      const u16* krow = kbase + (size_t)(nchunk + cc0 + l15) * ND + quad * 8;
      short8 kf0 = *(const short8*)(krow);
      short8 kf1 = *(const short8*)(krow + 32);
      floatx4 acc = {0.f, 0.f, 0.f, 0.f};
      acc = __builtin_amdgcn_mfma_f32_16x16x32_bf16(qa0, kf0, acc, 0, 0, 0);
      acc = __builtin_amdgcn_mfma_f32_16x16x32_bf16(qa1, kf1, acc, 0, 0, 0);
      int ccol = cc0 + l15;
#pragma unroll
      for (int r = 0; r < 4; ++r) {
        float e = __expf(acc[r] * 0.125f);
        rs[r] += e;
        P[(quad * 4 + r) * 520 + ccol] = f2b(e);
      }
    }
    __syncthreads();
    const u16* vp = vrow + nchunk + quad * 8;
#pragma unroll
    for (int kk = 0; kk < 16; ++kk) {
      short8 a2 = *(const short8*)&P[l15 * 520 + kk * 32 + quad * 8];
      short8 b2 = *(const short8*)(vp + kk * 32);
      c2 = __builtin_amdgcn_mfma_f32_16x16x32_bf16(a2, b2, c2, 0, 0, 0);
    }
    __syncthreads();
  }
#pragma unroll
  for (int r = 0; r < 4; ++r) {
    float v = rs[r];
    v += __shfl_xor(v, 1); v += __shfl_xor(v, 2);
    v += __shfl_xor(v, 4); v += __shfl_xor(v, 8);
    rs[r] = v;
  }
  if (l15 == 0) {
#pragma unroll
    for (int r = 0; r < 4; ++r) rsum[w][quad * 4 + r] = rs[r];
  }
#pragma unroll
  for (int r = 0; r < 4; ++r)
    fgt[(size_t)(b * NNN + m0 + quad * 4 + r) * ND + w * 16 + l15] = c2[r];
  __syncthreads();
  if (t < 16) {
    float s = rsum[0][t] + rsum[1][t] + rsum[2][t] + rsum[3][t];
    linv[b * NNN + m0 + t] = 1.f / s;
  }
}

// ---------------- A/B2 pre-GEMMs:  out[b][n][o] ----------------
__global__ __launch_bounds__(256) void k_ab(const float* __restrict__ f, const float* __restrict__ wl,
                                            float* __restrict__ Apre, float* __restrict__ Bpre) {
  __shared__ float fl[ND * 64];
  int t = threadIdx.x;
  int b = blockIdx.x >> 6;
  int n0 = (blockIdx.x & 63) << 6;
  for (int e = t; e < ND * 64; e += 256) {
    int d = e >> 6, c = e & 63;
    fl[e] = f[b * ND * NNN + d * NNN + n0 + c];
  }
  __syncthreads();
  int lane = t & 63;
  int w = __builtin_amdgcn_readfirstlane(t >> 6);
#pragma unroll 1
  for (int g = 0; g < 8; ++g) {
    float acc[8] = {0, 0, 0, 0, 0, 0, 0, 0};
    int p0 = w * 64 + g * 8;
    for (int d = 0; d < ND; ++d) {
      float fv = fl[d * 64 + lane];
#pragma unroll
      for (int u = 0; u < 8; ++u) {
        int p = p0 + u;
        int o = p & 127, sel = p >> 7;
        acc[u] += wl[o * 129 + sel * 64 + d] * fv;
      }
    }
#pragma unroll
    for (int u = 0; u < 8; ++u) {
      int p = p0 + u;
      int o = p & 127, sel = p >> 7;
      float* outp = sel ? Bpre : Apre;
      outp[(b * NNN + n0 + lane) * NO + o] = acc[u];
    }
  }
}

// ---------------- intra (unchanged) ----------------
__global__ __launch_bounds__(128) void k_intra(const float* __restrict__ Apre, const float* __restrict__ Bpre,
                                               const int* __restrict__ tidx, const float* __restrict__ td2,
                                               const float* __restrict__ wl, float* __restrict__ imax,
                                               float* __restrict__ imin, float* __restrict__ stats) {
  __shared__ int sidx[32 * NK];
  __shared__ float sdst[32 * NK];
  int t = threadIdx.x;
  int b = blockIdx.x >> 7;
  int n0 = (blockIdx.x & 127) << 5;
  for (int e = t; e < 32 * NK; e += 128) {
    int base = (b * NNN + n0 + (e >> 4)) * NK + (e & 15);
    sidx[e] = tidx[base];
    sdst[e] = sqrtf(td2[base]);
  }
  __syncthreads();
  int o = t;
  float w128 = wl[o * 129 + 128];
  float ssum = 0.f, ssq = 0.f;
  for (int c = 0; c < 32; ++c) {
    float a = Apre[(b * NNN + n0 + c) * NO + o];
    float mx = -3.4e38f, mn = 3.4e38f;
#pragma unroll
    for (int kx = 0; kx < NK; ++kx) {
      int id = sidx[c * NK + kx];
      float y = a + Bpre[(b * NNN + id) * NO + o] + w128 * sdst[c * NK + kx];
      mx = fmaxf(mx, y); mn = fminf(mn, y);
      ssum += y; ssq += y * y;
    }
    imax[(b * NO + o) * NNN + n0 + c] = mx;
    imin[(b * NO + o) * NNN + n0 + c] = mn;
  }
  atomicAdd(&stats[o], ssum);
  atomicAdd(&stats[NO + o], ssq);
}

// ---------------- sem: z = w_sem * (fgt[b][n][d] * linv[n])  -> [b][o][n] ----------------
__global__ __launch_bounds__(256) void k_sem(const float* __restrict__ fgt, const float* __restrict__ linv,
                                             const float* __restrict__ wsem, float* __restrict__ zsem) {
  __shared__ float fl[64 * 65];
  int t = threadIdx.x;
  int b = blockIdx.x >> 6;
  int n0 = (blockIdx.x & 63) << 6;
  for (int e = t; e < 64 * 64; e += 256) {
    int n = e >> 6, d = e & 63;
    fl[n * 65 + d] = fgt[(size_t)(b * NNN + n0 + n) * ND + d] * linv[b * NNN + n0 + n];
  }
  __syncthreads();
  int lane = t & 63;
  int ob = __builtin_amdgcn_readfirstlane((t >> 6) * 32);
#pragma unroll 1
  for (int g = 0; g < 4; ++g) {
    float acc[8] = {0, 0, 0, 0, 0, 0, 0, 0};
    for (int d = 0; d < ND; ++d) {
      float fv = fl[lane * 65 + d];
#pragma unroll
      for (int u = 0; u < 8; ++u) acc[u] += wsem[(ob + g * 8 + u) * ND + d] * fv;
    }
#pragma unroll
    for (int u = 0; u < 8; ++u)
      zsem[(b * NO + ob + g * 8 + u) * NNN + n0 + lane] = acc[u];
  }
}

// ---------------- per-channel sum/ssq (unchanged) ----------------
__global__ void k_stats(const float* __restrict__ zz, float* __restrict__ sout) {
  int o = blockIdx.x, t = threadIdx.x;
  float s = 0.f, q = 0.f;
  for (int b2 = 0; b2 < NB; ++b2) {
    const float* p = zz + (size_t)(b2 * NO + o) * NNN;
    for (int n = t; n < NNN; n += 256) { float v = p[n]; s += v; q += v * v; }
  }
#pragma unroll
  for (int off = 32; off; off >>= 1) { s += __shfl_down(s, off); q += __shfl_down(q, off); }
  __shared__ float rs[4], rq[4];
  int lane = t & 63, w = t >> 6;
  if (lane == 0) { rs[w] = s; rq[w] = q; }
  __syncthreads();
  if (t == 0) {
    sout[o]      = rs[0] + rs[1] + rs[2] + rs[3];
    sout[NO + o] = rq[0] + rq[1] + rq[2] + rq[3];
  }
}

// ---------------- finalize BN (unchanged) ----------------
__global__ void k_fin(const float* __restrict__ stats, const float* __restrict__ g,
                      const float* __restrict__ be, float cnt_inv, float* __restrict__ coef) {
  int o = threadIdx.x;
  float mean = stats[o] * cnt_inv;
  float var = stats[NO + o] * cnt_inv - mean * mean;
  var = var > 0.f ? var : 0.f;
  float a = g[o] * rsqrtf(var + BN_EPS);
  coef[o] = a;
  coef[NO + o] = be[o] - mean * a;
}

// ---------------- full (unchanged) ----------------
__global__ __launch_bounds__(256) void k_full(const float* __restrict__ imax, const float* __restrict__ imin,
                                              const float* __restrict__ zsem, const float* __restrict__ wfull,
                                              const float* __restrict__ coef, float* __restrict__ zfull) {
  __shared__ float fl[2 * NO * 64];
  int t = threadIdx.x;
  int b = blockIdx.x >> 6;
  int n0 = (blockIdx.x & 63) << 6;
  for (int e = t; e < 2 * NO * 64; e += 256) {
    int c = e >> 6, col = e & 63;
    float aa, bb, x;
    if (c < NO) {
      aa = coef[c]; bb = coef[NO + c];
      const float* src = (aa >= 0.f) ? imax : imin;
      x = src[(b * NO + c) * NNN + n0 + col];
    } else {
      int c2 = c - NO;
      aa = coef[2 * NO + c2]; bb = coef[3 * NO + c2];
      x = zsem[(b * NO + c2) * NNN + n0 + col];
    }
    float y = aa * x + bb;
    fl[e] = (y >= 0.f) ? y : NEG * y;
  }
  __syncthreads();
  int lane = t & 63;
  int ob = __builtin_amdgcn_readfirstlane((t >> 6) * 32);
#pragma unroll 1
  for (int g = 0; g < 4; ++g) {
    float acc[8] = {0, 0, 0, 0, 0, 0, 0, 0};
    for (int c = 0; c < 2 * NO; ++c) {
      float fv = fl[c * 64 + lane];
#pragma unroll
      for (int u = 0; u < 8; ++u) acc[u] += wfull[(ob + g * 8 + u) * (2 * NO) + c] * fv;
    }
#pragma unroll
    for (int u = 0; u < 8; ++u)
      zfull[(b * NO + ob + g * 8 + u) * NNN + n0 + lane] = acc[u];
  }
}

// ---------------- out = lrelu(a*z + b) ----------------
__global__ void k_out(const float* __restrict__ zfull, const float* __restrict__ coef,
                      float* __restrict__ out) {
  int gid = blockIdx.x * 256 + threadIdx.x;
  int o = (gid >> 12) & 127;
  float y = coef[o] * zfull[gid] + coef[NO + o];
  out[gid] = (y >= 0.f) ? y : NEG * y;
}

extern "C" void kernel_launch(void* const* d_in, const int* in_sizes, int n_in,
                              void* d_out, int out_size, void* d_ws, size_t ws_size,
                              hipStream_t stream) {
  (void)in_sizes; (void)n_in; (void)out_size; (void)ws_size;
  const float* f       = (const float*)d_in[0];
  const float* w_local = (const float*)d_in[1];
  const float* g_local = (const float*)d_in[2];
  const float* b_local = (const float*)d_in[3];
  const float* w_sem   = (const float*)d_in[4];
  const float* g_sem   = (const float*)d_in[5];
  const float* b_sem   = (const float*)d_in[6];
  const float* w_full  = (const float*)d_in[7];
  const float* g_full  = (const float*)d_in[8];
  const float* b_full  = (const float*)d_in[9];
  const float* wq = (const float*)d_in[10];
  const float* bq = (const float*)d_in[11];
  const float* wk = (const float*)d_in[12];
  const float* bk = (const float*)d_in[13];
  const float* wv = (const float*)d_in[14];
  const float* bv = (const float*)d_in[15];
  float* Wp = (float*)d_ws;
  u16* qb16 = (u16*)(Wp + OFF_Q);
  u16* kb16 = (u16*)(Wp + OFF_K);
  u16* vb16 = (u16*)(Wp + OFF_V);

  hipMemsetAsync(Wp + OFF_STATS, 0, 2 * NO * sizeof(float), stream);
  k_xx  <<<NB * NNN / 256, 256, 0, stream>>>(f, Wp + OFF_XX);
  k_qkv <<<dim3(NB * NNN / 64, 3), 256, 0, stream>>>(f, wq, bq, wk, bk, wv, bv, qb16, kb16, vb16);
  k_knn <<<NB * (NNN / 8), 256, 0, stream>>>(f, Wp + OFF_XX, (int*)(Wp + OFF_IDX), Wp + OFF_D2);
  k_attn<<<NB * (NNN / 16), 256, 0, stream>>>(qb16, kb16, vb16, Wp + OFF_FGT, Wp + OFF_LINV);
  k_ab  <<<NB * (NNN / 64), 256, 0, stream>>>(f, w_local, Wp + OFF_APRE, Wp + OFF_BPRE);
  k_intra<<<NB * (NNN / 32), 128, 0, stream>>>(Wp + OFF_APRE, Wp + OFF_BPRE,
                                               (const int*)(Wp + OFF_IDX), Wp + OFF_D2,
                                               w_local, Wp + OFF_IMAX, Wp + OFF_IMIN, Wp + OFF_STATS);
  k_sem <<<NB * (NNN / 64), 256, 0, stream>>>(Wp + OFF_FGT, Wp + OFF_LINV, w_sem, Wp + OFF_ZSEM);
  k_stats<<<NO, 256, 0, stream>>>(Wp + OFF_ZSEM, Wp + OFF_STATS + 2 * NO);
  k_fin <<<1, NO, 0, stream>>>(Wp + OFF_STATS,          g_local, b_local,
                               1.f / (float)(NB * NNN * NK), Wp + OFF_COEF);
  k_fin <<<1, NO, 0, stream>>>(Wp + OFF_STATS + 2 * NO, g_sem, b_sem,
                               1.f / (float)(NB * NNN), Wp + OFF_COEF + 2 * NO);
  k_full<<<NB * (NNN / 64), 256, 0, stream>>>(Wp + OFF_IMAX, Wp + OFF_IMIN, Wp + OFF_ZSEM,
                                              w_full, Wp + OFF_COEF, Wp + OFF_ZFULL);
  k_stats<<<NO, 256, 0, stream>>>(Wp + OFF_ZFULL, Wp + OFF_STATS + 4 * NO);
  k_fin <<<1, NO, 0, stream>>>(Wp + OFF_STATS + 4 * NO, g_full, b_full,
                               1.f / (float)(NB * NNN), Wp + OFF_COEF + 4 * NO);
  k_out <<<NB * NO * NNN / 256, 256, 0, stream>>>(Wp + OFF_ZFULL, Wp + OFF_COEF + 4 * NO,
                                                  (float*)d_out);
}

// Round 7
// 707.338 us; speedup vs baseline: 1.8462x; 1.0408x over previous
//
#include <hip/hip_runtime.h>
#include <math.h>

constexpr int NB = 4;      // batch
constexpr int ND = 64;     // feature dim
constexpr int NNN = 4096;  // points
constexpr int NO = 128;    // out channels
constexpr int NK = 16;     // k-nn
constexpr float NEG = 0.01f;
constexpr float BN_EPS = 1e-5f;

typedef unsigned short u16;
typedef unsigned int u32;
typedef __attribute__((ext_vector_type(8))) short short8;
typedef __attribute__((ext_vector_type(4))) float floatx4;

// workspace offsets (in floats)
constexpr int OFF_XX    = 0;
constexpr int OFF_IDX   = 16384;
constexpr int OFF_D2    = 278528;
constexpr int OFF_Q     = 540672;       // qb16 bf16 [b][n][d]
constexpr int OFF_K     = 1589248;      // kb16 bf16 [b][n][d]
constexpr int OFF_V     = 2637824;      // vb16 bf16 [b][d][n]
constexpr int OFF_FGT   = 3686400;      // fgt fp32 [b][n][d] (unnormalized)
constexpr int OFF_APRE  = 4734976;
constexpr int OFF_BPRE  = 6832128;
constexpr int OFF_IMAX  = 8929280;
constexpr int OFF_IMIN  = 11026432;
constexpr int OFF_ZSEM  = OFF_Q;
constexpr int OFF_ZFULL = OFF_V;
constexpr int OFF_STATS = 13123584;
constexpr int OFF_COEF  = 13124352;
constexpr int OFF_LINV  = 13125120;

__device__ __forceinline__ u16 f2b(float x) {       // fp32 -> bf16 RNE
  u32 u = __builtin_bit_cast(u32, x);
  u += 0x7fffu + ((u >> 16) & 1u);
  return (u16)(u >> 16);
}

// value-only max fold step via DPP (single v_max_f32 with fused DPP src)
template <int CTRL>
__device__ __forceinline__ float fmax_dpp(float v) {
  int b = __builtin_bit_cast(int, v);
  int s = __builtin_amdgcn_update_dpp(b, b, CTRL, 0xF, 0xF, false);
  return fmaxf(v, __builtin_bit_cast(float, s));
}
// (value,col) pair fold: larger value wins; tie -> keep left (smaller col by construction)
__device__ __forceinline__ void pairmax(float av, int ai, float bv, int bi, float& rv, int& ri) {
  bool tk = bv > av;
  rv = tk ? bv : av;
  ri = tk ? bi : ai;
}

// ---------------- xx[b][n] = sum_d f^2 ----------------
__global__ void k_xx(const float* __restrict__ f, float* __restrict__ xx) {
  int gid = blockIdx.x * 256 + threadIdx.x;
  int b = gid >> 12, n = gid & 4095;
  const float* fb = f + b * ND * NNN + n;
  float s = 0.f;
#pragma unroll
  for (int d = 0; d < ND; ++d) { float v = fb[d * NNN]; s += v * v; }
  xx[gid] = s;
}

// ---------------- q/k/v = W f + bias -> bf16 (q,k: [b][n][d]; v: [b][d][n]) ----------------
__global__ __launch_bounds__(256) void k_qkv(const float* __restrict__ f,
    const float* __restrict__ wq, const float* __restrict__ bq,
    const float* __restrict__ wk, const float* __restrict__ bk,
    const float* __restrict__ wv, const float* __restrict__ bv,
    u16* __restrict__ qb, u16* __restrict__ kb, u16* __restrict__ vb) {
  int sel = blockIdx.y;
  const float* W    = (sel == 0) ? wq : (sel == 1) ? wk : wv;
  const float* bias = (sel == 0) ? bq : (sel == 1) ? bk : bv;
  int t = threadIdx.x;
  int lane = t & 63;
  int og = __builtin_amdgcn_readfirstlane(t >> 6);
  int gcol = blockIdx.x * 64 + lane;
  int b = gcol >> 12, n = gcol & 4095;
  const float* fb = f + b * ND * NNN + n;
  float cv[64];
#pragma unroll
  for (int d = 0; d < ND; ++d) cv[d] = fb[d * NNN];
  float acc[16];
#pragma unroll 1
  for (int oi = 0; oi < 16; ++oi) {
    int o = og * 16 + oi;
    const float* wr = W + o * ND;
    float a = bias[o];
#pragma unroll
    for (int d = 0; d < ND; ++d) a += wr[d] * cv[d];
    acc[oi] = a;
  }
  if (sel == 2) {
#pragma unroll
    for (int oi = 0; oi < 16; ++oi)
      vb[(size_t)(b * ND + og * 16 + oi) * NNN + n] = f2b(acc[oi]);
  } else {
    short8 p0, p1;
#pragma unroll
    for (int oi = 0; oi < 8; ++oi) { p0[oi] = (short)f2b(acc[oi]); p1[oi] = (short)f2b(acc[8 + oi]); }
    u16* dst = (sel ? kb : qb) + (size_t)(b * NNN + n) * ND + og * 16;
    *(short8*)dst = p0;
    *(short8*)(dst + 8) = p1;
  }
}

// ---------------- kNN v6: 8 rows/block, col-halves of 2048, float4 loads,
// lane-leaf tournament: value-only DPP fold + ballot owner + incremental path update ----------------
__global__ __launch_bounds__(256, 4) void k_knn(const float* __restrict__ f, const float* __restrict__ xx,
                                                int* __restrict__ tidx, float* __restrict__ td2) {
  __shared__ __align__(16) float fm[ND * 8];   // [d][r] row fragments (2 KB)
  __shared__ __align__(16) float sl[4 * 2048]; // 4 rows x 2048 cols (32 KB)
  int t = threadIdx.x;
  int lane = t & 63;
  int w = __builtin_amdgcn_readfirstlane(t >> 6);
  int b = blockIdx.x >> 9;
  int m0 = (blockIdx.x & 511) << 3;
  const float* fb = f + b * ND * NNN;
  { int e = t;       int d = e >> 3, r = e & 7; fm[e] = fb[d * NNN + m0 + r]; }
  { int e = t + 256; int d = e >> 3, r = e & 7; fm[e] = fb[d * NNN + m0 + r]; }
  __syncthreads();
  float lv[2][2];                         // [half][stint] extraction value (rank = lane 0..15)
  int   li[2][2];                         // global col index
#pragma unroll
  for (int h = 0; h < 2; ++h) {
    // ---- phase 1 (bit-identical fma chain): acc[jj*32 + c*8 + r], col = h*2048 + jj*1024 + 4t + c ----
    float acc[64];
#pragma unroll
    for (int i = 0; i < 64; ++i) acc[i] = 0.f;
    for (int d = 0; d < ND; ++d) {
      const float* frow = fb + d * NNN + h * 2048 + 4 * t;
      float4 v0 = *(const float4*)(frow);
      float4 v1 = *(const float4*)(frow + 1024);
      float4 r0 = *(const float4*)&fm[d * 8];
      float4 r1 = *(const float4*)&fm[d * 8 + 4];
      float va0[4] = {v0.x, v0.y, v0.z, v0.w};
      float va1[4] = {v1.x, v1.y, v1.z, v1.w};
      float rr[8]  = {r0.x, r0.y, r0.z, r0.w, r1.x, r1.y, r1.z, r1.w};
#pragma unroll
      for (int c2 = 0; c2 < 4; ++c2)
#pragma unroll
        for (int r = 0; r < 8; ++r) {
          acc[c2 * 8 + r]      += va0[c2] * rr[r];
          acc[32 + c2 * 8 + r] += va1[c2] * rr[r];
        }
    }
    {
      const float* xrow = xx + b * NNN + h * 2048 + 4 * t;
      float4 x0 = *(const float4*)(xrow);
      float4 x1 = *(const float4*)(xrow + 1024);
      float xa0[4] = {x0.x, x0.y, x0.z, x0.w};
      float xa1[4] = {x1.x, x1.y, x1.z, x1.w};
#pragma unroll
      for (int c2 = 0; c2 < 4; ++c2)
#pragma unroll
        for (int r = 0; r < 8; ++r) {
          acc[c2 * 8 + r]      = 2.f * acc[c2 * 8 + r]      - xa0[c2];
          acc[32 + c2 * 8 + r] = 2.f * acc[32 + c2 * 8 + r] - xa1[c2];
        }
    }
    // ---- two stints: stage rows s*4..s*4+3, wave w selects row s*4+w ----
#pragma unroll
    for (int s = 0; s < 2; ++s) {
      __syncthreads();                    // prev stint/half reads done
#pragma unroll
      for (int r4 = 0; r4 < 4; ++r4) {
        int r = s * 4 + r4;
#pragma unroll
        for (int jj = 0; jj < 2; ++jj) {
          float4 w4;
          w4.x = acc[jj * 32 + 0 * 8 + r];
          w4.y = acc[jj * 32 + 1 * 8 + r];
          w4.z = acc[jj * 32 + 2 * 8 + r];
          w4.w = acc[jj * 32 + 3 * 8 + r];
          *(float4*)&sl[r4 * 2048 + jj * 1024 + 4 * t] = w4;
        }
      }
      __syncthreads();
      // ---- selection: 32 vals/lane (col = slot*64+lane), lane-leaf tournament ----
      float vals[32];
#pragma unroll
      for (int i = 0; i < 32; ++i) vals[i] = sl[w * 2048 + i * 64 + lane];
      // leaves: 8 groups of 4 (cols ascend with slot -> strict > keeps min col)
      float gv[8]; int gi[8];
#pragma unroll
      for (int g = 0; g < 8; ++g) {
        float v0 = vals[g * 4]; int i0 = (g * 4) * 64 + lane;
#pragma unroll
        for (int k2 = 1; k2 < 4; ++k2)
          pairmax(v0, i0, vals[g * 4 + k2], (g * 4 + k2) * 64 + lane, v0, i0);
        gv[g] = v0; gi[g] = i0;
      }
      // two-level in-lane tree
      float t1v[4]; int t1i[4];
      float t2v[2]; int t2i[2];
      float lvv; int lii;
#pragma unroll
      for (int p = 0; p < 4; ++p) pairmax(gv[2 * p], gi[2 * p], gv[2 * p + 1], gi[2 * p + 1], t1v[p], t1i[p]);
#pragma unroll
      for (int q = 0; q < 2; ++q) pairmax(t1v[2 * q], t1i[2 * q], t1v[2 * q + 1], t1i[2 * q + 1], t2v[q], t2i[q]);
      pairmax(t2v[0], t2i[0], t2v[1], t2i[1], lvv, lii);
      float selv = 0.f; int seli = 0;     // lanes 0..15 capture extraction kx==lane
#pragma unroll 1
      for (int kx = 0; kx < NK; ++kx) {
        // value-only wave max: 4 DPP + 2 shfl levels (one v_max each)
        float W = lvv;
        W = fmax_dpp<0xB1>(W);            // quad_perm [1,0,3,2]
        W = fmax_dpp<0x4E>(W);            // quad_perm [2,3,0,1]
        W = fmax_dpp<0x124>(W);           // row_ror:4
        W = fmax_dpp<0x128>(W);           // row_ror:8
        W = fmaxf(W, __shfl_xor(W, 16));
        W = fmaxf(W, __shfl_xor(W, 32));
        // owner = first lane whose lane-max equals W; winner col via readlane
        unsigned long long mk = __ballot(lvv == W);
        int lw = (int)__ffsll(mk) - 1;
        int wcol = __builtin_amdgcn_readlane(lii, lw);   // uniform col in half
        if (lane == kx) { selv = W; seli = wcol; }
        // remove winner (slot is uniform) + incremental path update
        int jw = wcol >> 6;               // slot 0..31
#pragma unroll
        for (int g = 0; g < 8; ++g)
          if (g == (jw >> 2)) {           // uniform scalar branch
#pragma unroll
            for (int k2 = 0; k2 < 4; ++k2)
              if (k2 == (jw & 3))
                vals[g * 4 + k2] = (lane == lw) ? -3.0e38f : vals[g * 4 + k2];
            float v0 = vals[g * 4]; int i0 = (g * 4) * 64 + lane;
#pragma unroll
            for (int k2 = 1; k2 < 4; ++k2)
              pairmax(v0, i0, vals[g * 4 + k2], (g * 4 + k2) * 64 + lane, v0, i0);
            gv[g] = v0; gi[g] = i0;
            int p = g >> 1;
            pairmax(gv[2 * p], gi[2 * p], gv[2 * p + 1], gi[2 * p + 1], t1v[p], t1i[p]);
            int q = p >> 1;
            pairmax(t1v[2 * q], t1i[2 * q], t1v[2 * q + 1], t1i[2 * q + 1], t2v[q], t2i[q]);
            pairmax(t2v[0], t2i[0], t2v[1], t2i[1], lvv, lii);
          }
      }
      lv[h][s] = selv; li[h][s] = h * 2048 + seli;
    }
  }
  // ---- stable merge of half-0 / half-1 top-16 lists (all h0 idx < h1 idx) ----
#pragma unroll
  for (int s = 0; s < 2; ++s) {
    int m = m0 + s * 4 + w;
    float xm = xx[b * NNN + m];
    float a   = lv[0][s]; int ai  = li[0][s];
    float bb2 = lv[1][s]; int bi2 = li[1][s];
    int cntB = 0, cntA = 0;
#pragma unroll
    for (int j = 0; j < 16; ++j) {
      float bj = __shfl(bb2, j);
      cntB += (bj > a) ? 1 : 0;
      float aj = __shfl(a, j);
      cntA += (aj >= bb2) ? 1 : 0;
    }
    if (lane < 16) {
      int base = (b * NNN + m) * NK;
      int rA = lane + cntB;
      int rB = lane + cntA;
      if (rA < NK) {
        float dd = xm - a;
        tidx[base + rA] = ai;
        td2[base + rA] = dd > 0.f ? dd : 0.f;
      }
      if (rB < NK) {
        float dd = xm - bb2;
        tidx[base + rB] = bi2;
        td2[base + rB] = dd > 0.f ? dd : 0.f;
      }
    }
  }
}

// ---------------- attention: MFMA bf16, 16 rows/block, P-chunk (16x512) in LDS ----------------
__global__ __launch_bounds__(256) void k_attn(const u16* __restrict__ qb,
                                              const u16* __restrict__ kb,
                                              const u16* __restrict__ vb,
                                              float* __restrict__ fgt,
                                              float* __restrict__ linv) {
  __shared__ __align__(16) u16 P[16 * 520];
  __shared__ float rsum[4][16];
  int t = threadIdx.x;
  int lane = t & 63;
  int w = __builtin_amdgcn_readfirstlane(t >> 6);
  int quad = lane >> 4;
  int l15 = lane & 15;
  int b = blockIdx.x >> 8;
  int m0 = (blockIdx.x & 255) << 4;
  const u16* qrow = qb + (size_t)(b * NNN + m0 + l15) * ND + quad * 8;
  short8 qa0 = *(const short8*)(qrow);
  short8 qa1 = *(const short8*)(qrow + 32);
  const u16* kbase = kb + (size_t)b * NNN * ND;
  const u16* vrow  = vb + (size_t)(b * ND + w * 16 + l15) * NNN;
  floatx4 c2 = {0.f, 0.f, 0.f, 0.f};
  float rs[4] = {0.f, 0.f, 0.f, 0.f};
#pragma unroll 1
  for (int it = 0; it < 8; ++it) {
    int nchunk = it * 512;
#pragma unroll 1
    for (int ct = 0; ct < 8; ++ct) {
      int cc0 = (w * 8 + ct) * 16;
      const u16* krow = kbase + (size_t)(nchunk + cc0 + l15) * ND + quad * 8;
      short8 kf0 = *(const short8*)(krow);
      short8 kf1 = *(const short8*)(krow + 32);
      floatx4 acc = {0.f, 0.f, 0.f, 0.f};
      acc = __builtin_amdgcn_mfma_f32_16x16x32_bf16(qa0, kf0, acc, 0, 0, 0);
      acc = __builtin_amdgcn_mfma_f32_16x16x32_bf16(qa1, kf1, acc, 0, 0, 0);
      int ccol = cc0 + l15;
#pragma unroll
      for (int r = 0; r < 4; ++r) {
        float e = __expf(acc[r] * 0.125f);
        rs[r] += e;
        P[(quad * 4 + r) * 520 + ccol] = f2b(e);
      }
    }
    __syncthreads();
    const u16* vp = vrow + nchunk + quad * 8;
#pragma unroll
    for (int kk = 0; kk < 16; ++kk) {
      short8 a2 = *(const short8*)&P[l15 * 520 + kk * 32 + quad * 8];
      short8 b2 = *(const short8*)(vp + kk * 32);
      c2 = __builtin_amdgcn_mfma_f32_16x16x32_bf16(a2, b2, c2, 0, 0, 0);
    }
    __syncthreads();
  }
#pragma unroll
  for (int r = 0; r < 4; ++r) {
    float v = rs[r];
    v += __shfl_xor(v, 1); v += __shfl_xor(v, 2);
    v += __shfl_xor(v, 4); v += __shfl_xor(v, 8);
    rs[r] = v;
  }
  if (l15 == 0) {
#pragma unroll
    for (int r = 0; r < 4; ++r) rsum[w][quad * 4 + r] = rs[r];
  }
#pragma unroll
  for (int r = 0; r < 4; ++r)
    fgt[(size_t)(b * NNN + m0 + quad * 4 + r) * ND + w * 16 + l15] = c2[r];
  __syncthreads();
  if (t < 16) {
    float s = rsum[0][t] + rsum[1][t] + rsum[2][t] + rsum[3][t];
    linv[b * NNN + m0 + t] = 1.f / s;
  }
}

// ---------------- A/B2 pre-GEMMs:  out[b][n][o] ----------------
__global__ __launch_bounds__(256) void k_ab(const float* __restrict__ f, const float* __restrict__ wl,
                                            float* __restrict__ Apre, float* __restrict__ Bpre) {
  __shared__ float fl[ND * 64];
  int t = threadIdx.x;
  int b = blockIdx.x >> 6;
  int n0 = (blockIdx.x & 63) << 6;
  for (int e = t; e < ND * 64; e += 256) {
    int d = e >> 6, c = e & 63;
    fl[e] = f[b * ND * NNN + d * NNN + n0 + c];
  }
  __syncthreads();
  int lane = t & 63;
  int w = __builtin_amdgcn_readfirstlane(t >> 6);
#pragma unroll 1
  for (int g = 0; g < 8; ++g) {
    float acc[8] = {0, 0, 0, 0, 0, 0, 0, 0};
    int p0 = w * 64 + g * 8;
    for (int d = 0; d < ND; ++d) {
      float fv = fl[d * 64 + lane];
#pragma unroll
      for (int u = 0; u < 8; ++u) {
        int p = p0 + u;
        int o = p & 127, sel = p >> 7;
        acc[u] += wl[o * 129 + sel * 64 + d] * fv;
      }
    }
#pragma unroll
    for (int u = 0; u < 8; ++u) {
      int p = p0 + u;
      int o = p & 127, sel = p >> 7;
      float* outp = sel ? Bpre : Apre;
      outp[(b * NNN + n0 + lane) * NO + o] = acc[u];
    }
  }
}

// ---------------- intra (unchanged) ----------------
__global__ __launch_bounds__(128) void k_intra(const float* __restrict__ Apre, const float* __restrict__ Bpre,
                                               const int* __restrict__ tidx, const float* __restrict__ td2,
                                               const float* __restrict__ wl, float* __restrict__ imax,
                                               float* __restrict__ imin, float* __restrict__ stats) {
  __shared__ int sidx[32 * NK];
  __shared__ float sdst[32 * NK];
  int t = threadIdx.x;
  int b = blockIdx.x >> 7;
  int n0 = (blockIdx.x & 127) << 5;
  for (int e = t; e < 32 * NK; e += 128) {
    int base = (b * NNN + n0 + (e >> 4)) * NK + (e & 15);
    sidx[e] = tidx[base];
    sdst[e] = sqrtf(td2[base]);
  }
  __syncthreads();
  int o = t;
  float w128 = wl[o * 129 + 128];
  float ssum = 0.f, ssq = 0.f;
  for (int c = 0; c < 32; ++c) {
    float a = Apre[(b * NNN + n0 + c) * NO + o];
    float mx = -3.4e38f, mn = 3.4e38f;
#pragma unroll
    for (int kx = 0; kx < NK; ++kx) {
      int id = sidx[c * NK + kx];
      float y = a + Bpre[(b * NNN + id) * NO + o] + w128 * sdst[c * NK + kx];
      mx = fmaxf(mx, y); mn = fminf(mn, y);
      ssum += y; ssq += y * y;
    }
    imax[(b * NO + o) * NNN + n0 + c] = mx;
    imin[(b * NO + o) * NNN + n0 + c] = mn;
  }
  atomicAdd(&stats[o], ssum);
  atomicAdd(&stats[NO + o], ssq);
}

// ---------------- sem: z = w_sem * (fgt[b][n][d] * linv[n])  -> [b][o][n] ----------------
__global__ __launch_bounds__(256) void k_sem(const float* __restrict__ fgt, const float* __restrict__ linv,
                                             const float* __restrict__ wsem, float* __restrict__ zsem) {
  __shared__ float fl[64 * 65];
  int t = threadIdx.x;
  int b = blockIdx.x >> 6;
  int n0 = (blockIdx.x & 63) << 6;
  for (int e = t; e < 64 * 64; e += 256) {
    int n = e >> 6, d = e & 63;
    fl[n * 65 + d] = fgt[(size_t)(b * NNN + n0 + n) * ND + d] * linv[b * NNN + n0 + n];
  }
  __syncthreads();
  int lane = t & 63;
  int ob = __builtin_amdgcn_readfirstlane((t >> 6) * 32);
#pragma unroll 1
  for (int g = 0; g < 4; ++g) {
    float acc[8] = {0, 0, 0, 0, 0, 0, 0, 0};
    for (int d = 0; d < ND; ++d) {
      float fv = fl[lane * 65 + d];
#pragma unroll
      for (int u = 0; u < 8; ++u) acc[u] += wsem[(ob + g * 8 + u) * ND + d] * fv;
    }
#pragma unroll
    for (int u = 0; u < 8; ++u)
      zsem[(b * NO + ob + g * 8 + u) * NNN + n0 + lane] = acc[u];
  }
}

// ---------------- per-channel sum/ssq (unchanged) ----------------
__global__ void k_stats(const float* __restrict__ zz, float* __restrict__ sout) {
  int o = blockIdx.x, t = threadIdx.x;
  float s = 0.f, q = 0.f;
  for (int b2 = 0; b2 < NB; ++b2) {
    const float* p = zz + (size_t)(b2 * NO + o) * NNN;
    for (int n = t; n < NNN; n += 256) { float v = p[n]; s += v; q += v * v; }
  }
#pragma unroll
  for (int off = 32; off; off >>= 1) { s += __shfl_down(s, off); q += __shfl_down(q, off); }
  __shared__ float rs[4], rq[4];
  int lane = t & 63, w = t >> 6;
  if (lane == 0) { rs[w] = s; rq[w] = q; }
  __syncthreads();
  if (t == 0) {
    sout[o]      = rs[0] + rs[1] + rs[2] + rs[3];
    sout[NO + o] = rq[0] + rq[1] + rq[2] + rq[3];
  }
}

// ---------------- finalize BN (unchanged) ----------------
__global__ void k_fin(const float* __restrict__ stats, const float* __restrict__ g,
                      const float* __restrict__ be, float cnt_inv, float* __restrict__ coef) {
  int o = threadIdx.x;
  float mean = stats[o] * cnt_inv;
  float var = stats[NO + o] * cnt_inv - mean * mean;
  var = var > 0.f ? var : 0.f;
  float a = g[o] * rsqrtf(var + BN_EPS);
  coef[o] = a;
  coef[NO + o] = be[o] - mean * a;
}

// ---------------- full (unchanged) ----------------
__global__ __launch_bounds__(256) void k_full(const float* __restrict__ imax, const float* __restrict__ imin,
                                              const float* __restrict__ zsem, const float* __restrict__ wfull,
                                              const float* __restrict__ coef, float* __restrict__ zfull) {
  __shared__ float fl[2 * NO * 64];
  int t = threadIdx.x;
  int b = blockIdx.x >> 6;
  int n0 = (blockIdx.x & 63) << 6;
  for (int e = t; e < 2 * NO * 64; e += 256) {
    int c = e >> 6, col = e & 63;
    float aa, bb, x;
    if (c < NO) {
      aa = coef[c]; bb = coef[NO + c];
      const float* src = (aa >= 0.f) ? imax : imin;
      x = src[(b * NO + c) * NNN + n0 + col];
    } else {
      int c2 = c - NO;
      aa = coef[2 * NO + c2]; bb = coef[3 * NO + c2];
      x = zsem[(b * NO + c2) * NNN + n0 + col];
    }
    float y = aa * x + bb;
    fl[e] = (y >= 0.f) ? y : NEG * y;
  }
  __syncthreads();
  int lane = t & 63;
  int ob = __builtin_amdgcn_readfirstlane((t >> 6) * 32);
#pragma unroll 1
  for (int g = 0; g < 4; ++g) {
    float acc[8] = {0, 0, 0, 0, 0, 0, 0, 0};
    for (int c = 0; c < 2 * NO; ++c) {
      float fv = fl[c * 64 + lane];
#pragma unroll
      for (int u = 0; u < 8; ++u) acc[u] += wfull[(ob + g * 8 + u) * (2 * NO) + c] * fv;
    }
#pragma unroll
    for (int u = 0; u < 8; ++u)
      zfull[(b * NO + ob + g * 8 + u) * NNN + n0 + lane] = acc[u];
  }
}

// ---------------- out = lrelu(a*z + b) ----------------
__global__ void k_out(const float* __restrict__ zfull, const float* __restrict__ coef,
                      float* __restrict__ out) {
  int gid = blockIdx.x * 256 + threadIdx.x;
  int o = (gid >> 12) & 127;
  float y = coef[o] * zfull[gid] + coef[NO + o];
  out[gid] = (y >= 0.f) ? y : NEG * y;
}

extern "C" void kernel_launch(void* const* d_in, const int* in_sizes, int n_in,
                              void* d_out, int out_size, void* d_ws, size_t ws_size,
                              hipStream_t stream) {
  (void)in_sizes; (void)n_in; (void)out_size; (void)ws_size;
  const float* f       = (const float*)d_in[0];
  const float* w_local = (const float*)d_in[1];
  const float* g_local = (const float*)d_in[2];
  const float* b_local = (const float*)d_in[3];
  const float* w_sem   = (const float*)d_in[4];
  const float* g_sem   = (const float*)d_in[5];
  const float* b_sem   = (const float*)d_in[6];
  const float* w_full  = (const float*)d_in[7];
  const float* g_full  = (const float*)d_in[8];
  const float* b_full  = (const float*)d_in[9];
  const float* wq = (const float*)d_in[10];
  const float* bq = (const float*)d_in[11];
  const float* wk = (const float*)d_in[12];
  const float* bk = (const float*)d_in[13];
  const float* wv = (const float*)d_in[14];
  const float* bv = (const float*)d_in[15];
  float* Wp = (float*)d_ws;
  u16* qb16 = (u16*)(Wp + OFF_Q);
  u16* kb16 = (u16*)(Wp + OFF_K);
  u16* vb16 = (u16*)(Wp + OFF_V);

  hipMemsetAsync(Wp + OFF_STATS, 0, 2 * NO * sizeof(float), stream);
  k_xx  <<<NB * NNN / 256, 256, 0, stream>>>(f, Wp + OFF_XX);
  k_qkv <<<dim3(NB * NNN / 64, 3), 256, 0, stream>>>(f, wq, bq, wk, bk, wv, bv, qb16, kb16, vb16);
  k_knn <<<NB * (NNN / 8), 256, 0, stream>>>(f, Wp + OFF_XX, (int*)(Wp + OFF_IDX), Wp + OFF_D2);
  k_attn<<<NB * (NNN / 16), 256, 0, stream>>>(qb16, kb16, vb16, Wp + OFF_FGT, Wp + OFF_LINV);
  k_ab  <<<NB * (NNN / 64), 256, 0, stream>>>(f, w_local, Wp + OFF_APRE, Wp + OFF_BPRE);
  k_intra<<<NB * (NNN / 32), 128, 0, stream>>>(Wp + OFF_APRE, Wp + OFF_BPRE,
                                               (const int*)(Wp + OFF_IDX), Wp + OFF_D2,
                                               w_local, Wp + OFF_IMAX, Wp + OFF_IMIN, Wp + OFF_STATS);
  k_sem <<<NB * (NNN / 64), 256, 0, stream>>>(Wp + OFF_FGT, Wp + OFF_LINV, w_sem, Wp + OFF_ZSEM);
  k_stats<<<NO, 256, 0, stream>>>(Wp + OFF_ZSEM, Wp + OFF_STATS + 2 * NO);
  k_fin <<<1, NO, 0, stream>>>(Wp + OFF_STATS,          g_local, b_local,
                               1.f / (float)(NB * NNN * NK), Wp + OFF_COEF);
  k_fin <<<1, NO, 0, stream>>>(Wp + OFF_STATS + 2 * NO, g_sem, b_sem,
                               1.f / (float)(NB * NNN), Wp + OFF_COEF + 2 * NO);
  k_full<<<NB * (NNN / 64), 256, 0, stream>>>(Wp + OFF_IMAX, Wp + OFF_IMIN, Wp + OFF_ZSEM,
                                              w_full, Wp + OFF_COEF, Wp + OFF_ZFULL);
  k_stats<<<NO, 256, 0, stream>>>(Wp + OFF_ZFULL, Wp + OFF_STATS + 4 * NO);
  k_fin <<<1, NO, 0, stream>>>(Wp + OFF_STATS + 4 * NO, g_full, b_full,
                               1.f / (float)(NB * NNN), Wp + OFF_COEF + 4 * NO);
  k_out <<<NB * NO * NNN / 256, 256, 0, stream>>>(Wp + OFF_ZFULL, Wp + OFF_COEF + 4 * NO,
                                                  (float*)d_out);
}